// Round 2
// baseline (3168.346 us; speedup 1.0000x reference)
//
#include <hip/hip_runtime.h>
#include <hip/hip_bf16.h>

#define D_ 128
#define L_ 65536
#define C_ 32768
#define E_ 262144

typedef __hip_bfloat16 bf16;

// flags[0] = 1 if float inputs are fp32 (else bf16); flags[1] = 1 if edge idx int32 (else int64)
__global__ void detect_k(const unsigned short* __restrict__ wmem,
                         const int* __restrict__ li, int* __restrict__ flags) {
    int t = blockIdx.x * 512 + threadIdx.x;
    if (t < 8192) {
        unsigned short h = wmem[2 * t];  // even halfword: bf16 value OR fp32 low-mantissa
        float v = __bfloat162float(*(const bf16*)&h);
        if (!(fabsf(v) < 0.5f)) atomicOr(&flags[0], 1);  // catches big values and NaN
    }
    if (t < 2048) {
        if (li[2 * t + 1] != 0) atomicOr(&flags[1], 1);  // nonzero odd word => int32
    }
}

__global__ void cvt_k(const void* __restrict__ s, float* __restrict__ d, int n,
                      const int* __restrict__ flags) {
    int i = blockIdx.x * 256 + threadIdx.x;
    if (i >= n) return;
    d[i] = flags[0] ? ((const float*)s)[i] : __bfloat162float(((const bf16*)s)[i]);
}

__global__ void init_emb_k(const void* __restrict__ v, float* __restrict__ emb, int n,
                           const int* __restrict__ flags) {
    int i = blockIdx.x * 256 + threadIdx.x;
    if (i >= n) return;
    int j = i & (D_ - 1);
    emb[i] = flags[0] ? ((const float*)v)[j] : __bfloat162float(((const bf16*)v)[j]);
}

__global__ void fix_idx_k(const int* __restrict__ s, int* __restrict__ d, int n, int maxv,
                          const int* __restrict__ flags) {
    int i = blockIdx.x * 256 + threadIdx.x;
    if (i >= n) return;
    int v = flags[1] ? s[i] : s[2 * i];  // flags[1]==0 => int64: take low word
    d[i] = min(max(v, 0), maxv - 1);
}

__global__ void degree_k(const int* __restrict__ li, const int* __restrict__ ci,
                         float* __restrict__ ld, float* __restrict__ cd) {
    int e = blockIdx.x * 256 + threadIdx.x;
    if (e < E_) {
        atomicAdd(&ld[li[e]], 1.0f);
        atomicAdd(&cd[ci[e]], 1.0f);
    }
}

__global__ void norm_k(const int* __restrict__ li, const int* __restrict__ ci,
                       const float* __restrict__ ld, const float* __restrict__ cd,
                       float* __restrict__ inv) {
    int e = blockIdx.x * 256 + threadIdx.x;
    if (e < E_) inv[e] = 1.0f / (sqrtf(ld[li[e]]) * sqrtf(cd[ci[e]]));
}

// One wave (64 lanes) per edge; each lane owns 2 of the 128 features.
__global__ void scatter_k(const int* __restrict__ li, const int* __restrict__ ci,
                          const float* __restrict__ inv,
                          const float* __restrict__ lmsg, const float* __restrict__ cmsg,
                          float* __restrict__ laggr, float* __restrict__ caggr) {
    int wid = (blockIdx.x * 256 + threadIdx.x) >> 6;
    int lane = threadIdx.x & 63;
    if (wid >= E_) return;
    int l = li[wid], c = ci[wid];
    float s = inv[wid];
    const float2 lm = *(const float2*)&lmsg[l * D_ + 2 * lane];
    atomicAdd(&caggr[c * D_ + 2 * lane + 0], lm.x * s);
    atomicAdd(&caggr[c * D_ + 2 * lane + 1], lm.y * s);
    const float2 cm = *(const float2*)&cmsg[c * D_ + 2 * lane];
    atomicAdd(&laggr[l * D_ + 2 * lane + 0], cm.x * s);
    atomicAdd(&laggr[l * D_ + 2 * lane + 1], cm.y * s);
}

// out[N x 128] = act( concatK(A0,A1,A2)[N x K] @ W[K x 128] + bias ).
// Block: 256 threads, tile 128 rows x 128 cols, per-thread 8x8 register tile.
// SWAP: row r reads source row r^1 (literal pair swap for the l2l MLP).
template <int RELU, int SWAP>
__global__ __launch_bounds__(256) void gemm_k(
    const float* __restrict__ A0, const float* __restrict__ A1, const float* __restrict__ A2,
    const float* __restrict__ Wm, const float* __restrict__ bias,
    float* __restrict__ out, int K) {
    __shared__ float x_s[32][128];  // [k][row]
    __shared__ float w_s[32][128];  // [k][col]
    const int t = threadIdx.x;
    const int tr = t >> 4, tc = t & 15;
    const int br0 = blockIdx.x * 128;
    float acc[8][8];
#pragma unroll
    for (int i = 0; i < 8; i++)
#pragma unroll
        for (int j = 0; j < 8; j++) acc[i][j] = 0.0f;

    for (int kt = 0; kt < K; kt += 32) {
        const float* As = (kt < 128) ? A0 : (kt < 256) ? A1 : A2;
        const int koff = kt & 127;
#pragma unroll
        for (int i = 0; i < 4; i++) {
            int f = t + 256 * i;
            int r = f >> 3, kq = f & 7;
            int gr = br0 + r;
            if (SWAP) gr ^= 1;
            const float4 v = *(const float4*)&As[gr * D_ + koff + 4 * kq];
            x_s[4 * kq + 0][r] = v.x;
            x_s[4 * kq + 1][r] = v.y;
            x_s[4 * kq + 2][r] = v.z;
            x_s[4 * kq + 3][r] = v.w;
        }
#pragma unroll
        for (int i = 0; i < 4; i++) {
            int f = t + 256 * i;
            int kk = f >> 5, jq = f & 31;
            *(float4*)&w_s[kk][4 * jq] = *(const float4*)&Wm[(kt + kk) * D_ + 4 * jq];
        }
        __syncthreads();
#pragma unroll
        for (int k = 0; k < 32; k++) {
            float a[8], b[8];
            *(float4*)&a[0] = *(const float4*)&x_s[k][8 * tr];
            *(float4*)&a[4] = *(const float4*)&x_s[k][8 * tr + 4];
            *(float4*)&b[0] = *(const float4*)&w_s[k][8 * tc];
            *(float4*)&b[4] = *(const float4*)&w_s[k][8 * tc + 4];
#pragma unroll
            for (int i = 0; i < 8; i++)
#pragma unroll
                for (int j = 0; j < 8; j++) acc[i][j] = fmaf(a[i], b[j], acc[i][j]);
        }
        __syncthreads();
    }
    float bv[8];
    *(float4*)&bv[0] = *(const float4*)&bias[8 * tc];
    *(float4*)&bv[4] = *(const float4*)&bias[8 * tc + 4];
#pragma unroll
    for (int i = 0; i < 8; i++) {
        const int gr = br0 + 8 * tr + i;
        float o[8];
#pragma unroll
        for (int j = 0; j < 8; j++) {
            float v = acc[i][j] + bv[j];
            if (RELU) v = fmaxf(v, 0.0f);
            o[j] = v;
        }
        *(float4*)&out[gr * D_ + 8 * tc + 0] = *(float4*)&o[0];
        *(float4*)&out[gr * D_ + 8 * tc + 4] = *(float4*)&o[4];
    }
}

__global__ void out_k(const float* __restrict__ s, void* __restrict__ d, int n,
                      const int* __restrict__ flags) {
    int i = blockIdx.x * 256 + threadIdx.x;
    if (i >= n) return;
    if (flags[0]) ((float*)d)[i] = s[i];
    else ((bf16*)d)[i] = __float2bfloat16(s[i]);
}

extern "C" void kernel_launch(void* const* d_in, const int* in_sizes, int n_in,
                              void* d_out, int out_size, void* d_ws, size_t ws_size,
                              hipStream_t stream) {
    const int* li_raw = (const int*)d_in[0];
    const int* ci_raw = (const int*)d_in[1];

    // workspace layout (floats)
    float* ws = (float*)d_ws;
    float* lbuf0 = ws;                               // L*D
    float* lbuf1 = lbuf0 + (size_t)L_ * D_;          // L*D
    float* l2lb  = lbuf1 + (size_t)L_ * D_;          // L*D
    float* laggr = l2lb + (size_t)L_ * D_;           // L*D (aliased as MLP hidden buf)
    float* cbuf0 = laggr + (size_t)L_ * D_;          // C*D
    float* cbuf1 = cbuf0 + (size_t)C_ * D_;          // C*D
    float* caggr = cbuf1 + (size_t)C_ * D_;          // C*D
    float* invn  = caggr + (size_t)C_ * D_;          // E
    float* ldeg  = invn + E_;                        // L
    float* cdeg  = ldeg + L_;                        // C
    float* wf    = cdeg + C_;                        // 181,248 floats fp32 weights
    int*   li    = (int*)(wf + 181248);              // E ints
    int*   ci    = li + E_;                          // E ints
    int*   flags = ci + E_;                          // 2 ints
    float* hbuf  = laggr;                            // alias: dead before laggr memset

    float* w_l2c1 = wf +      0; float* w_l2c2 = wf +  16384;
    float* w_c2l1 = wf +  32768; float* w_c2l2 = wf +  49152;
    float* w_l2l1 = wf +  65536; float* w_l2l2 = wf +  81920;
    float* w_cu   = wf +  98304; float* w_lu   = wf + 131072;
    float* bb     = wf + 180224;
    float* b_l2c1 = bb + 0;   float* b_l2c2 = bb + 128;
    float* b_c2l1 = bb + 256; float* b_c2l2 = bb + 384;
    float* b_l2l1 = bb + 512; float* b_l2l2 = bb + 640;
    float* b_cu   = bb + 768; float* b_lu   = bb + 896;

    // --- dtype detection (device-side, graph-safe) ---
    hipMemsetAsync(flags, 0, 2 * sizeof(int), stream);
    detect_k<<<16, 512, 0, stream>>>((const unsigned short*)d_in[4], li_raw, flags);

    // --- index cleanup ---
    fix_idx_k<<<E_ / 256, 256, 0, stream>>>(li_raw, li, E_, L_, flags);
    fix_idx_k<<<E_ / 256, 256, 0, stream>>>(ci_raw, ci, E_, C_, flags);

    // --- weight/bias conversion ---
    struct Job { int idx; float* dst; int n; };
    const Job jobs[16] = {
        {4, w_l2c1, 16384}, {6, w_l2c2, 16384}, {8, w_c2l1, 16384}, {10, w_c2l2, 16384},
        {12, w_l2l1, 16384}, {14, w_l2l2, 16384}, {16, w_cu, 32768}, {18, w_lu, 49152},
        {5, b_l2c1, 128}, {7, b_l2c2, 128}, {9, b_c2l1, 128}, {11, b_c2l2, 128},
        {13, b_l2l1, 128}, {15, b_l2l2, 128}, {17, b_cu, 128}, {19, b_lu, 128},
    };
    for (int j = 0; j < 16; j++)
        cvt_k<<<(jobs[j].n + 255) / 256, 256, 0, stream>>>(d_in[jobs[j].idx], jobs[j].dst,
                                                           jobs[j].n, flags);

    // degrees -> per-edge 1/(sqrt(ldeg)*sqrt(cdeg))
    hipMemsetAsync(ldeg, 0, (size_t)(L_ + C_) * sizeof(float), stream);
    degree_k<<<E_ / 256, 256, 0, stream>>>(li, ci, ldeg, cdeg);
    norm_k<<<E_ / 256, 256, 0, stream>>>(li, ci, ldeg, cdeg, invn);

    // broadcast-init embeddings
    init_emb_k<<<(L_ * D_) / 256, 256, 0, stream>>>(d_in[2], lbuf0, L_ * D_, flags);
    init_emb_k<<<(C_ * D_) / 256, 256, 0, stream>>>(d_in[3], cbuf0, C_ * D_, flags);

    float* l_cur = lbuf0; float* l_nxt = lbuf1;
    float* c_cur = cbuf0; float* c_nxt = cbuf1;

    for (int it = 0; it < 4; it++) {
        gemm_k<1, 0><<<L_ / 128, 256, 0, stream>>>(l_cur, nullptr, nullptr, w_l2c1, b_l2c1, hbuf, 128);
        gemm_k<0, 0><<<L_ / 128, 256, 0, stream>>>(hbuf, nullptr, nullptr, w_l2c2, b_l2c2, l_nxt, 128);
        gemm_k<1, 0><<<C_ / 128, 256, 0, stream>>>(c_cur, nullptr, nullptr, w_c2l1, b_c2l1, hbuf, 128);
        gemm_k<0, 0><<<C_ / 128, 256, 0, stream>>>(hbuf, nullptr, nullptr, w_c2l2, b_c2l2, c_nxt, 128);
        gemm_k<1, 1><<<L_ / 128, 256, 0, stream>>>(l_cur, nullptr, nullptr, w_l2l1, b_l2l1, hbuf, 128);
        gemm_k<0, 0><<<L_ / 128, 256, 0, stream>>>(hbuf, nullptr, nullptr, w_l2l2, b_l2l2, l2lb, 128);
        hipMemsetAsync(laggr, 0, (size_t)L_ * D_ * sizeof(float), stream);
        hipMemsetAsync(caggr, 0, (size_t)C_ * D_ * sizeof(float), stream);
        scatter_k<<<E_ / 4, 256, 0, stream>>>(li, ci, invn, l_nxt, c_nxt, laggr, caggr);
        gemm_k<0, 0><<<C_ / 128, 256, 0, stream>>>(c_cur, caggr, nullptr, w_cu, b_cu, c_nxt, 256);
        gemm_k<0, 0><<<L_ / 128, 256, 0, stream>>>(l_cur, laggr, l2lb, w_lu, b_lu, l_nxt, 384);
        float* tmp = l_cur; l_cur = l_nxt; l_nxt = tmp;
        tmp = c_cur; c_cur = c_nxt; c_nxt = tmp;
    }
    out_k<<<(L_ * D_) / 256, 256, 0, stream>>>(l_cur, d_out, L_ * D_, flags);
}

// Round 3
// 1744.439 us; speedup vs baseline: 1.8163x; 1.8163x over previous
//
#include <hip/hip_runtime.h>
#include <hip/hip_bf16.h>

#define D_ 128
#define L_ 65536
#define C_ 32768
#define E_ 262144

typedef __hip_bfloat16 bf16;

// flags[0] = 1 if float inputs are fp32 (else bf16); flags[1] = 1 if edge idx int32 (else int64)
__global__ void detect_k(const unsigned short* __restrict__ wmem,
                         const int* __restrict__ li, int* __restrict__ flags) {
    int t = blockIdx.x * 512 + threadIdx.x;
    if (t < 8192) {
        unsigned short h = wmem[2 * t];
        float v = __bfloat162float(*(const bf16*)&h);
        if (!(fabsf(v) < 0.5f)) atomicOr(&flags[0], 1);
    }
    if (t < 2048) {
        if (li[2 * t + 1] != 0) atomicOr(&flags[1], 1);
    }
}

__global__ void cvt_k(const void* __restrict__ s, float* __restrict__ d, int n,
                      const int* __restrict__ flags) {
    int i = blockIdx.x * 256 + threadIdx.x;
    if (i >= n) return;
    d[i] = flags[0] ? ((const float*)s)[i] : __bfloat162float(((const bf16*)s)[i]);
}

__global__ void init_emb_k(const void* __restrict__ v, float* __restrict__ emb, int n,
                           const int* __restrict__ flags) {
    int i = blockIdx.x * 256 + threadIdx.x;
    if (i >= n) return;
    int j = i & (D_ - 1);
    emb[i] = flags[0] ? ((const float*)v)[j] : __bfloat162float(((const bf16*)v)[j]);
}

__global__ void fix_idx_k(const int* __restrict__ s, int* __restrict__ d, int n, int maxv,
                          const int* __restrict__ flags) {
    int i = blockIdx.x * 256 + threadIdx.x;
    if (i >= n) return;
    int v = flags[1] ? s[i] : s[2 * i];
    d[i] = min(max(v, 0), maxv - 1);
}

__global__ void degree_k(const int* __restrict__ li, const int* __restrict__ ci,
                         int* __restrict__ ld, int* __restrict__ cd) {
    int e = blockIdx.x * 256 + threadIdx.x;
    if (e < E_) {
        atomicAdd(&ld[li[e]], 1);
        atomicAdd(&cd[ci[e]], 1);
    }
}

__global__ void norm_k(const int* __restrict__ li, const int* __restrict__ ci,
                       const int* __restrict__ ld, const int* __restrict__ cd,
                       float* __restrict__ inv) {
    int e = blockIdx.x * 256 + threadIdx.x;
    if (e < E_) inv[e] = rsqrtf((float)ld[li[e]] * (float)cd[ci[e]]);
}

// --- two-level exclusive scan (tiles of 256) ---
__global__ void scan1_k(const int* __restrict__ in, int* __restrict__ out,
                        int* __restrict__ bsum, int n) {
    __shared__ int s[256];
    int i = blockIdx.x * 256 + threadIdx.x;
    int v = (i < n) ? in[i] : 0;
    s[threadIdx.x] = v;
    __syncthreads();
#pragma unroll
    for (int off = 1; off < 256; off <<= 1) {
        int t = (threadIdx.x >= off) ? s[threadIdx.x - off] : 0;
        __syncthreads();
        s[threadIdx.x] += t;
        __syncthreads();
    }
    if (i < n) out[i] = s[threadIdx.x] - v;  // exclusive
    if (threadIdx.x == 255) bsum[blockIdx.x] = s[255];
}

__global__ void scan2_k(int* __restrict__ b, int nb) {
    __shared__ int s[256];
    int v = (threadIdx.x < nb) ? b[threadIdx.x] : 0;
    s[threadIdx.x] = v;
    __syncthreads();
#pragma unroll
    for (int off = 1; off < 256; off <<= 1) {
        int t = (threadIdx.x >= off) ? s[threadIdx.x - off] : 0;
        __syncthreads();
        s[threadIdx.x] += t;
        __syncthreads();
    }
    if (threadIdx.x < nb) b[threadIdx.x] = s[threadIdx.x] - v;
}

__global__ void scan3_k(int* __restrict__ out, const int* __restrict__ bsum, int n) {
    int i = blockIdx.x * 256 + threadIdx.x;
    if (i < n) out[i] += bsum[blockIdx.x];
}

// CSR placement: write (other endpoint, edge weight) into each node's slot range.
__global__ void place_k(const int* __restrict__ li, const int* __restrict__ ci,
                        const float* __restrict__ inv,
                        int* __restrict__ lcur, int* __restrict__ ccur,
                        int* __restrict__ l_other, float* __restrict__ l_w,
                        int* __restrict__ c_other, float* __restrict__ c_w) {
    int e = blockIdx.x * 256 + threadIdx.x;
    if (e >= E_) return;
    int l = li[e], c = ci[e];
    float w = inv[e];
    int p = atomicAdd(&ccur[c], 1);
    c_other[p] = l; c_w[p] = w;
    int q = atomicAdd(&lcur[l], 1);
    l_other[q] = c; l_w[q] = w;
}

// Pull-aggregation: one wave per destination node, lanes own 2 of 128 features.
__global__ __launch_bounds__(256) void gather_k(
    const int* __restrict__ ptr, const int* __restrict__ deg,
    const int* __restrict__ other, const float* __restrict__ w,
    const float* __restrict__ msg, float* __restrict__ out, int n) {
    int node = (blockIdx.x * 256 + threadIdx.x) >> 6;
    int lane = threadIdx.x & 63;
    if (node >= n) return;
    int s = ptr[node], cnt = deg[node];
    float2 acc = {0.0f, 0.0f};
    for (int k = 0; k < cnt; k++) {
        int o = other[s + k];
        float ww = w[s + k];
        const float2 m = *(const float2*)&msg[o * D_ + 2 * lane];
        acc.x = fmaf(m.x, ww, acc.x);
        acc.y = fmaf(m.y, ww, acc.y);
    }
    *(float2*)&out[node * D_ + 2 * lane] = acc;
}

// out[N x 128] = act( concatK(A0,A1,A2)[N x K] @ W[K x 128] + bias ).
template <int RELU, int SWAP>
__global__ __launch_bounds__(256) void gemm_k(
    const float* __restrict__ A0, const float* __restrict__ A1, const float* __restrict__ A2,
    const float* __restrict__ Wm, const float* __restrict__ bias,
    float* __restrict__ out, int K) {
    __shared__ float x_s[32][128];
    __shared__ float w_s[32][128];
    const int t = threadIdx.x;
    const int tr = t >> 4, tc = t & 15;
    const int br0 = blockIdx.x * 128;
    float acc[8][8];
#pragma unroll
    for (int i = 0; i < 8; i++)
#pragma unroll
        for (int j = 0; j < 8; j++) acc[i][j] = 0.0f;

    for (int kt = 0; kt < K; kt += 32) {
        const float* As = (kt < 128) ? A0 : (kt < 256) ? A1 : A2;
        const int koff = kt & 127;
#pragma unroll
        for (int i = 0; i < 4; i++) {
            int f = t + 256 * i;
            int r = f >> 3, kq = f & 7;
            int gr = br0 + r;
            if (SWAP) gr ^= 1;
            const float4 v = *(const float4*)&As[gr * D_ + koff + 4 * kq];
            x_s[4 * kq + 0][r] = v.x;
            x_s[4 * kq + 1][r] = v.y;
            x_s[4 * kq + 2][r] = v.z;
            x_s[4 * kq + 3][r] = v.w;
        }
#pragma unroll
        for (int i = 0; i < 4; i++) {
            int f = t + 256 * i;
            int kk = f >> 5, jq = f & 31;
            *(float4*)&w_s[kk][4 * jq] = *(const float4*)&Wm[(kt + kk) * D_ + 4 * jq];
        }
        __syncthreads();
#pragma unroll
        for (int k = 0; k < 32; k++) {
            float a[8], b[8];
            *(float4*)&a[0] = *(const float4*)&x_s[k][8 * tr];
            *(float4*)&a[4] = *(const float4*)&x_s[k][8 * tr + 4];
            *(float4*)&b[0] = *(const float4*)&w_s[k][8 * tc];
            *(float4*)&b[4] = *(const float4*)&w_s[k][8 * tc + 4];
#pragma unroll
            for (int i = 0; i < 8; i++)
#pragma unroll
                for (int j = 0; j < 8; j++) acc[i][j] = fmaf(a[i], b[j], acc[i][j]);
        }
        __syncthreads();
    }
    float bv[8];
    *(float4*)&bv[0] = *(const float4*)&bias[8 * tc];
    *(float4*)&bv[4] = *(const float4*)&bias[8 * tc + 4];
#pragma unroll
    for (int i = 0; i < 8; i++) {
        const int gr = br0 + 8 * tr + i;
        float o[8];
#pragma unroll
        for (int j = 0; j < 8; j++) {
            float v = acc[i][j] + bv[j];
            if (RELU) v = fmaxf(v, 0.0f);
            o[j] = v;
        }
        *(float4*)&out[gr * D_ + 8 * tc + 0] = *(float4*)&o[0];
        *(float4*)&out[gr * D_ + 8 * tc + 4] = *(float4*)&o[4];
    }
}

__global__ void out_k(const float* __restrict__ s, void* __restrict__ d, int n,
                      const int* __restrict__ flags) {
    int i = blockIdx.x * 256 + threadIdx.x;
    if (i >= n) return;
    if (flags[0]) ((float*)d)[i] = s[i];
    else ((bf16*)d)[i] = __float2bfloat16(s[i]);
}

extern "C" void kernel_launch(void* const* d_in, const int* in_sizes, int n_in,
                              void* d_out, int out_size, void* d_ws, size_t ws_size,
                              hipStream_t stream) {
    const int* li_raw = (const int*)d_in[0];
    const int* ci_raw = (const int*)d_in[1];

    // ---- workspace layout ----
    float* ws = (float*)d_ws;
    float* lbuf0 = ws;                               // L*D
    float* lbuf1 = lbuf0 + (size_t)L_ * D_;          // L*D
    float* l2lb  = lbuf1 + (size_t)L_ * D_;          // L*D
    float* laggr = l2lb + (size_t)L_ * D_;           // L*D (aliased as MLP hidden buf)
    float* cbuf0 = laggr + (size_t)L_ * D_;          // C*D
    float* cbuf1 = cbuf0 + (size_t)C_ * D_;          // C*D
    float* caggr = cbuf1 + (size_t)C_ * D_;          // C*D
    float* invn  = caggr + (size_t)C_ * D_;          // E
    float* l_w   = invn + E_;                        // E
    float* c_w   = l_w + E_;                         // E
    float* wf    = c_w + E_;                         // 181,248 floats fp32 weights
    int*   li    = (int*)(wf + 181248);              // E
    int*   ci    = li + E_;                          // E
    int*   l_other = ci + E_;                        // E
    int*   c_other = l_other + E_;                   // E
    int*   ldegi = c_other + E_;                     // L   (ldegi..ccur contiguous: zeroed together where needed)
    int*   cdegi = ldegi + L_;                       // C
    int*   lptr  = cdegi + C_;                       // L
    int*   cptr  = lptr + L_;                        // C
    int*   lcur  = cptr + C_;                        // L
    int*   ccur  = lcur + L_;                        // C
    int*   bsum  = ccur + C_;                        // 256 scratch for scans
    int*   flags = bsum + 256;                       // 2
    float* hbuf  = laggr;                            // alias: dead before gather writes laggr

    float* w_l2c1 = wf +      0; float* w_l2c2 = wf +  16384;
    float* w_c2l1 = wf +  32768; float* w_c2l2 = wf +  49152;
    float* w_l2l1 = wf +  65536; float* w_l2l2 = wf +  81920;
    float* w_cu   = wf +  98304; float* w_lu   = wf + 131072;
    float* bb     = wf + 180224;
    float* b_l2c1 = bb + 0;   float* b_l2c2 = bb + 128;
    float* b_c2l1 = bb + 256; float* b_c2l2 = bb + 384;
    float* b_l2l1 = bb + 512; float* b_l2l2 = bb + 640;
    float* b_cu   = bb + 768; float* b_lu   = bb + 896;

    // --- dtype detection (device-side, graph-safe) ---
    hipMemsetAsync(flags, 0, 2 * sizeof(int), stream);
    detect_k<<<16, 512, 0, stream>>>((const unsigned short*)d_in[4], li_raw, flags);

    // --- index cleanup ---
    fix_idx_k<<<E_ / 256, 256, 0, stream>>>(li_raw, li, E_, L_, flags);
    fix_idx_k<<<E_ / 256, 256, 0, stream>>>(ci_raw, ci, E_, C_, flags);

    // --- weight/bias conversion ---
    struct Job { int idx; float* dst; int n; };
    const Job jobs[16] = {
        {4, w_l2c1, 16384}, {6, w_l2c2, 16384}, {8, w_c2l1, 16384}, {10, w_c2l2, 16384},
        {12, w_l2l1, 16384}, {14, w_l2l2, 16384}, {16, w_cu, 32768}, {18, w_lu, 49152},
        {5, b_l2c1, 128}, {7, b_l2c2, 128}, {9, b_c2l1, 128}, {11, b_c2l2, 128},
        {13, b_l2l1, 128}, {15, b_l2l2, 128}, {17, b_cu, 128}, {19, b_lu, 128},
    };
    for (int j = 0; j < 16; j++)
        cvt_k<<<(jobs[j].n + 255) / 256, 256, 0, stream>>>(d_in[jobs[j].idx], jobs[j].dst,
                                                           jobs[j].n, flags);

    // --- CSR build: degrees -> exclusive scan -> per-edge norm -> placement ---
    hipMemsetAsync(ldegi, 0, (size_t)(L_ + C_) * sizeof(int), stream);
    degree_k<<<E_ / 256, 256, 0, stream>>>(li, ci, ldegi, cdegi);

    scan1_k<<<L_ / 256, 256, 0, stream>>>(ldegi, lptr, bsum, L_);
    scan2_k<<<1, 256, 0, stream>>>(bsum, L_ / 256);
    scan3_k<<<L_ / 256, 256, 0, stream>>>(lptr, bsum, L_);
    scan1_k<<<C_ / 256, 256, 0, stream>>>(cdegi, cptr, bsum, C_);
    scan2_k<<<1, 256, 0, stream>>>(bsum, C_ / 256);
    scan3_k<<<C_ / 256, 256, 0, stream>>>(cptr, bsum, C_);

    norm_k<<<E_ / 256, 256, 0, stream>>>(li, ci, ldegi, cdegi, invn);

    hipMemcpyAsync(lcur, lptr, (size_t)L_ * sizeof(int), hipMemcpyDeviceToDevice, stream);
    hipMemcpyAsync(ccur, cptr, (size_t)C_ * sizeof(int), hipMemcpyDeviceToDevice, stream);
    place_k<<<E_ / 256, 256, 0, stream>>>(li, ci, invn, lcur, ccur,
                                          l_other, l_w, c_other, c_w);

    // --- broadcast-init embeddings ---
    init_emb_k<<<(L_ * D_) / 256, 256, 0, stream>>>(d_in[2], lbuf0, L_ * D_, flags);
    init_emb_k<<<(C_ * D_) / 256, 256, 0, stream>>>(d_in[3], cbuf0, C_ * D_, flags);

    float* l_cur = lbuf0; float* l_nxt = lbuf1;
    float* c_cur = cbuf0; float* c_nxt = cbuf1;

    for (int it = 0; it < 4; it++) {
        // node-level messages (hbuf==laggr is free during this phase)
        gemm_k<1, 0><<<L_ / 128, 256, 0, stream>>>(l_cur, nullptr, nullptr, w_l2c1, b_l2c1, hbuf, 128);
        gemm_k<0, 0><<<L_ / 128, 256, 0, stream>>>(hbuf, nullptr, nullptr, w_l2c2, b_l2c2, l_nxt, 128);
        gemm_k<1, 0><<<C_ / 128, 256, 0, stream>>>(c_cur, nullptr, nullptr, w_c2l1, b_c2l1, hbuf, 128);
        gemm_k<0, 0><<<C_ / 128, 256, 0, stream>>>(hbuf, nullptr, nullptr, w_c2l2, b_c2l2, c_nxt, 128);
        gemm_k<1, 1><<<L_ / 128, 256, 0, stream>>>(l_cur, nullptr, nullptr, w_l2l1, b_l2l1, hbuf, 128);
        gemm_k<0, 0><<<L_ / 128, 256, 0, stream>>>(hbuf, nullptr, nullptr, w_l2l2, b_l2l2, l2lb, 128);
        // pull-aggregation (no atomics, no memsets)
        gather_k<<<C_ / 4, 256, 0, stream>>>(cptr, cdegi, c_other, c_w, l_nxt, caggr, C_);
        gather_k<<<L_ / 4, 256, 0, stream>>>(lptr, ldegi, l_other, l_w, c_nxt, laggr, L_);
        // updates: c_new = [c,agg]@w_cu+b ; l_new = [l,agg,l2l]@w_lu+b
        gemm_k<0, 0><<<C_ / 128, 256, 0, stream>>>(c_cur, caggr, nullptr, w_cu, b_cu, c_nxt, 256);
        gemm_k<0, 0><<<L_ / 128, 256, 0, stream>>>(l_cur, laggr, l2lb, w_lu, b_lu, l_nxt, 384);
        float* tmp = l_cur; l_cur = l_nxt; l_nxt = tmp;
        tmp = c_cur; c_cur = c_nxt; c_nxt = tmp;
    }
    out_k<<<(L_ * D_) / 256, 256, 0, stream>>>(l_cur, d_out, L_ * D_, flags);
}

// Round 4
// 1660.708 us; speedup vs baseline: 1.9078x; 1.0504x over previous
//
#include <hip/hip_runtime.h>
#include <hip/hip_bf16.h>

#define D_ 128
#define L_ 65536
#define C_ 32768
#define E_ 262144

typedef __hip_bfloat16 bf16;

// flags[0] = 1 if float inputs are fp32 (else bf16); flags[1] = 1 if edge idx int32 (else int64)
__global__ void detect_k(const unsigned short* __restrict__ wmem,
                         const int* __restrict__ li, int* __restrict__ flags) {
    int t = blockIdx.x * 512 + threadIdx.x;
    if (t < 8192) {
        unsigned short h = wmem[2 * t];
        float v = __bfloat162float(*(const bf16*)&h);
        if (!(fabsf(v) < 0.5f)) atomicOr(&flags[0], 1);
    }
    if (t < 2048) {
        if (li[2 * t + 1] != 0) atomicOr(&flags[1], 1);
    }
}

__global__ void cvt_k(const void* __restrict__ s, float* __restrict__ d, int n,
                      const int* __restrict__ flags) {
    int i = blockIdx.x * 256 + threadIdx.x;
    if (i >= n) return;
    d[i] = flags[0] ? ((const float*)s)[i] : __bfloat162float(((const bf16*)s)[i]);
}

__global__ void init_emb_k(const void* __restrict__ v, float* __restrict__ emb, int n,
                           const int* __restrict__ flags) {
    int i = blockIdx.x * 256 + threadIdx.x;
    if (i >= n) return;
    int j = i & (D_ - 1);
    emb[i] = flags[0] ? ((const float*)v)[j] : __bfloat162float(((const bf16*)v)[j]);
}

__global__ void fix_idx_k(const int* __restrict__ s, int* __restrict__ d, int n, int maxv,
                          const int* __restrict__ flags) {
    int i = blockIdx.x * 256 + threadIdx.x;
    if (i >= n) return;
    int v = flags[1] ? s[i] : s[2 * i];
    d[i] = min(max(v, 0), maxv - 1);
}

__global__ void degree_k(const int* __restrict__ li, const int* __restrict__ ci,
                         int* __restrict__ ld, int* __restrict__ cd) {
    int e = blockIdx.x * 256 + threadIdx.x;
    if (e < E_) {
        atomicAdd(&ld[li[e]], 1);
        atomicAdd(&cd[ci[e]], 1);
    }
}

__global__ void norm_k(const int* __restrict__ li, const int* __restrict__ ci,
                       const int* __restrict__ ld, const int* __restrict__ cd,
                       float* __restrict__ inv) {
    int e = blockIdx.x * 256 + threadIdx.x;
    if (e < E_) inv[e] = rsqrtf((float)ld[li[e]] * (float)cd[ci[e]]);
}

// --- two-level exclusive scan (tiles of 256) ---
__global__ void scan1_k(const int* __restrict__ in, int* __restrict__ out,
                        int* __restrict__ bsum, int n) {
    __shared__ int s[256];
    int i = blockIdx.x * 256 + threadIdx.x;
    int v = (i < n) ? in[i] : 0;
    s[threadIdx.x] = v;
    __syncthreads();
#pragma unroll
    for (int off = 1; off < 256; off <<= 1) {
        int t = (threadIdx.x >= off) ? s[threadIdx.x - off] : 0;
        __syncthreads();
        s[threadIdx.x] += t;
        __syncthreads();
    }
    if (i < n) out[i] = s[threadIdx.x] - v;  // exclusive
    if (threadIdx.x == 255) bsum[blockIdx.x] = s[255];
}

__global__ void scan2_k(int* __restrict__ b, int nb) {
    __shared__ int s[256];
    int v = (threadIdx.x < nb) ? b[threadIdx.x] : 0;
    s[threadIdx.x] = v;
    __syncthreads();
#pragma unroll
    for (int off = 1; off < 256; off <<= 1) {
        int t = (threadIdx.x >= off) ? s[threadIdx.x - off] : 0;
        __syncthreads();
        s[threadIdx.x] += t;
        __syncthreads();
    }
    if (threadIdx.x < nb) b[threadIdx.x] = s[threadIdx.x] - v;
}

__global__ void scan3_k(int* __restrict__ out, const int* __restrict__ bsum, int n) {
    int i = blockIdx.x * 256 + threadIdx.x;
    if (i < n) out[i] += bsum[blockIdx.x];
}

// CSR placement: write (other endpoint, edge weight) into each node's slot range.
__global__ void place_k(const int* __restrict__ li, const int* __restrict__ ci,
                        const float* __restrict__ inv,
                        int* __restrict__ lcur, int* __restrict__ ccur,
                        int* __restrict__ l_other, float* __restrict__ l_w,
                        int* __restrict__ c_other, float* __restrict__ c_w) {
    int e = blockIdx.x * 256 + threadIdx.x;
    if (e >= E_) return;
    int l = li[e], c = ci[e];
    float w = inv[e];
    int p = atomicAdd(&ccur[c], 1);
    c_other[p] = l; c_w[p] = w;
    int q = atomicAdd(&lcur[l], 1);
    l_other[q] = c; l_w[q] = w;
}

// Pull-aggregation: one wave per destination node, lanes own 2 of 128 features.
__global__ __launch_bounds__(256) void gather_k(
    const int* __restrict__ ptr, const int* __restrict__ deg,
    const int* __restrict__ other, const float* __restrict__ w,
    const float* __restrict__ msg, float* __restrict__ out, int n) {
    int node = (blockIdx.x * 256 + threadIdx.x) >> 6;
    int lane = threadIdx.x & 63;
    if (node >= n) return;
    int s = ptr[node], cnt = deg[node];
    float2 acc = {0.0f, 0.0f};
    for (int k = 0; k < cnt; k++) {
        int o = other[s + k];
        float ww = w[s + k];
        const float2 m = *(const float2*)&msg[o * D_ + 2 * lane];
        acc.x = fmaf(m.x, ww, acc.x);
        acc.y = fmaf(m.y, ww, acc.y);
    }
    *(float2*)&out[node * D_ + 2 * lane] = acc;
}

// out[N x 128] = act( concatK(A0,A1,A2)[N x K] @ W[K x 128] + bias ).
// Block: 256 threads, tile 128 rows x 128 cols, per-thread 8x8 register tile.
// Thread (tr,tc): rows 8*tr..8*tr+7, cols {4*tc..4*tc+3} U {64+4*tc..64+4*tc+3}
// (split cols -> w_s b128 reads are 2-way/bank = free; launch_bounds(256,2)
//  -> VGPR budget 256 so the 8x8 acc tile stays in registers, no scratch spill)
template <int RELU, int SWAP>
__global__ __launch_bounds__(256, 2) void gemm_k(
    const float* __restrict__ A0, const float* __restrict__ A1, const float* __restrict__ A2,
    const float* __restrict__ Wm, const float* __restrict__ bias,
    float* __restrict__ out, int K) {
    __shared__ float x_s[32][128];  // [k][row]
    __shared__ float w_s[32][128];  // [k][col]
    const int t = threadIdx.x;
    const int tr = t >> 4, tc = t & 15;
    const int br0 = blockIdx.x * 128;
    float acc[8][8];
#pragma unroll
    for (int i = 0; i < 8; i++)
#pragma unroll
        for (int j = 0; j < 8; j++) acc[i][j] = 0.0f;

    for (int kt = 0; kt < K; kt += 32) {
        const float* As = (kt < 128) ? A0 : (kt < 256) ? A1 : A2;
        const int koff = kt & 127;
#pragma unroll
        for (int i = 0; i < 4; i++) {
            int f = t + 256 * i;
            int r = f >> 3, kq = f & 7;
            int gr = br0 + r;
            if (SWAP) gr ^= 1;
            const float4 v = *(const float4*)&As[gr * D_ + koff + 4 * kq];
            x_s[4 * kq + 0][r] = v.x;
            x_s[4 * kq + 1][r] = v.y;
            x_s[4 * kq + 2][r] = v.z;
            x_s[4 * kq + 3][r] = v.w;
        }
#pragma unroll
        for (int i = 0; i < 4; i++) {
            int f = t + 256 * i;
            int kk = f >> 5, jq = f & 31;
            *(float4*)&w_s[kk][4 * jq] = *(const float4*)&Wm[(kt + kk) * D_ + 4 * jq];
        }
        __syncthreads();
#pragma unroll
        for (int k = 0; k < 32; k++) {
            float a[8], b[8];
            *(float4*)&a[0] = *(const float4*)&x_s[k][8 * tr];
            *(float4*)&a[4] = *(const float4*)&x_s[k][8 * tr + 4];
            *(float4*)&b[0] = *(const float4*)&w_s[k][4 * tc];        // cols 4tc..4tc+3
            *(float4*)&b[4] = *(const float4*)&w_s[k][64 + 4 * tc];   // cols 64+4tc..
#pragma unroll
            for (int i = 0; i < 8; i++)
#pragma unroll
                for (int j = 0; j < 8; j++) acc[i][j] = fmaf(a[i], b[j], acc[i][j]);
        }
        __syncthreads();
    }
    float bv[8];
    *(float4*)&bv[0] = *(const float4*)&bias[4 * tc];
    *(float4*)&bv[4] = *(const float4*)&bias[64 + 4 * tc];
#pragma unroll
    for (int i = 0; i < 8; i++) {
        const int gr = br0 + 8 * tr + i;
        float o[8];
#pragma unroll
        for (int j = 0; j < 8; j++) {
            float v = acc[i][j] + bv[j];
            if (RELU) v = fmaxf(v, 0.0f);
            o[j] = v;
        }
        *(float4*)&out[gr * D_ + 4 * tc]      = *(float4*)&o[0];
        *(float4*)&out[gr * D_ + 64 + 4 * tc] = *(float4*)&o[4];
    }
}

__global__ void out_k(const float* __restrict__ s, void* __restrict__ d, int n,
                      const int* __restrict__ flags) {
    int i = blockIdx.x * 256 + threadIdx.x;
    if (i >= n) return;
    if (flags[0]) ((float*)d)[i] = s[i];
    else ((bf16*)d)[i] = __float2bfloat16(s[i]);
}

extern "C" void kernel_launch(void* const* d_in, const int* in_sizes, int n_in,
                              void* d_out, int out_size, void* d_ws, size_t ws_size,
                              hipStream_t stream) {
    const int* li_raw = (const int*)d_in[0];
    const int* ci_raw = (const int*)d_in[1];

    // ---- workspace layout ----
    float* ws = (float*)d_ws;
    float* lbuf0 = ws;                               // L*D
    float* lbuf1 = lbuf0 + (size_t)L_ * D_;          // L*D
    float* l2lb  = lbuf1 + (size_t)L_ * D_;          // L*D
    float* laggr = l2lb + (size_t)L_ * D_;           // L*D (aliased as MLP hidden buf)
    float* cbuf0 = laggr + (size_t)L_ * D_;          // C*D
    float* cbuf1 = cbuf0 + (size_t)C_ * D_;          // C*D
    float* caggr = cbuf1 + (size_t)C_ * D_;          // C*D
    float* invn  = caggr + (size_t)C_ * D_;          // E
    float* l_w   = invn + E_;                        // E
    float* c_w   = l_w + E_;                         // E
    float* wf    = c_w + E_;                         // 181,248 floats fp32 weights
    int*   li    = (int*)(wf + 181248);              // E
    int*   ci    = li + E_;                          // E
    int*   l_other = ci + E_;                        // E
    int*   c_other = l_other + E_;                   // E
    int*   ldegi = c_other + E_;                     // L
    int*   cdegi = ldegi + L_;                       // C
    int*   lptr  = cdegi + C_;                       // L
    int*   cptr  = lptr + L_;                        // C
    int*   lcur  = cptr + C_;                        // L
    int*   ccur  = lcur + L_;                        // C
    int*   bsum  = ccur + C_;                        // 256 scratch for scans
    int*   flags = bsum + 256;                       // 2
    float* hbuf  = laggr;                            // alias: dead before gather writes laggr

    float* w_l2c1 = wf +      0; float* w_l2c2 = wf +  16384;
    float* w_c2l1 = wf +  32768; float* w_c2l2 = wf +  49152;
    float* w_l2l1 = wf +  65536; float* w_l2l2 = wf +  81920;
    float* w_cu   = wf +  98304; float* w_lu   = wf + 131072;
    float* bb     = wf + 180224;
    float* b_l2c1 = bb + 0;   float* b_l2c2 = bb + 128;
    float* b_c2l1 = bb + 256; float* b_c2l2 = bb + 384;
    float* b_l2l1 = bb + 512; float* b_l2l2 = bb + 640;
    float* b_cu   = bb + 768; float* b_lu   = bb + 896;

    // --- dtype detection (device-side, graph-safe) ---
    hipMemsetAsync(flags, 0, 2 * sizeof(int), stream);
    detect_k<<<16, 512, 0, stream>>>((const unsigned short*)d_in[4], li_raw, flags);

    // --- index cleanup ---
    fix_idx_k<<<E_ / 256, 256, 0, stream>>>(li_raw, li, E_, L_, flags);
    fix_idx_k<<<E_ / 256, 256, 0, stream>>>(ci_raw, ci, E_, C_, flags);

    // --- weight/bias conversion ---
    struct Job { int idx; float* dst; int n; };
    const Job jobs[16] = {
        {4, w_l2c1, 16384}, {6, w_l2c2, 16384}, {8, w_c2l1, 16384}, {10, w_c2l2, 16384},
        {12, w_l2l1, 16384}, {14, w_l2l2, 16384}, {16, w_cu, 32768}, {18, w_lu, 49152},
        {5, b_l2c1, 128}, {7, b_l2c2, 128}, {9, b_c2l1, 128}, {11, b_c2l2, 128},
        {13, b_l2l1, 128}, {15, b_l2l2, 128}, {17, b_cu, 128}, {19, b_lu, 128},
    };
    for (int j = 0; j < 16; j++)
        cvt_k<<<(jobs[j].n + 255) / 256, 256, 0, stream>>>(d_in[jobs[j].idx], jobs[j].dst,
                                                           jobs[j].n, flags);

    // --- CSR build: degrees -> exclusive scan -> per-edge norm -> placement ---
    hipMemsetAsync(ldegi, 0, (size_t)(L_ + C_) * sizeof(int), stream);
    degree_k<<<E_ / 256, 256, 0, stream>>>(li, ci, ldegi, cdegi);

    scan1_k<<<L_ / 256, 256, 0, stream>>>(ldegi, lptr, bsum, L_);
    scan2_k<<<1, 256, 0, stream>>>(bsum, L_ / 256);
    scan3_k<<<L_ / 256, 256, 0, stream>>>(lptr, bsum, L_);
    scan1_k<<<C_ / 256, 256, 0, stream>>>(cdegi, cptr, bsum, C_);
    scan2_k<<<1, 256, 0, stream>>>(bsum, C_ / 256);
    scan3_k<<<C_ / 256, 256, 0, stream>>>(cptr, bsum, C_);

    norm_k<<<E_ / 256, 256, 0, stream>>>(li, ci, ldegi, cdegi, invn);

    hipMemcpyAsync(lcur, lptr, (size_t)L_ * sizeof(int), hipMemcpyDeviceToDevice, stream);
    hipMemcpyAsync(ccur, cptr, (size_t)C_ * sizeof(int), hipMemcpyDeviceToDevice, stream);
    place_k<<<E_ / 256, 256, 0, stream>>>(li, ci, invn, lcur, ccur,
                                          l_other, l_w, c_other, c_w);

    // --- broadcast-init embeddings ---
    init_emb_k<<<(L_ * D_) / 256, 256, 0, stream>>>(d_in[2], lbuf0, L_ * D_, flags);
    init_emb_k<<<(C_ * D_) / 256, 256, 0, stream>>>(d_in[3], cbuf0, C_ * D_, flags);

    float* l_cur = lbuf0; float* l_nxt = lbuf1;
    float* c_cur = cbuf0; float* c_nxt = cbuf1;

    for (int it = 0; it < 4; it++) {
        // node-level messages (hbuf==laggr is free during this phase)
        gemm_k<1, 0><<<L_ / 128, 256, 0, stream>>>(l_cur, nullptr, nullptr, w_l2c1, b_l2c1, hbuf, 128);
        gemm_k<0, 0><<<L_ / 128, 256, 0, stream>>>(hbuf, nullptr, nullptr, w_l2c2, b_l2c2, l_nxt, 128);
        gemm_k<1, 0><<<C_ / 128, 256, 0, stream>>>(c_cur, nullptr, nullptr, w_c2l1, b_c2l1, hbuf, 128);
        gemm_k<0, 0><<<C_ / 128, 256, 0, stream>>>(hbuf, nullptr, nullptr, w_c2l2, b_c2l2, c_nxt, 128);
        gemm_k<1, 1><<<L_ / 128, 256, 0, stream>>>(l_cur, nullptr, nullptr, w_l2l1, b_l2l1, hbuf, 128);
        gemm_k<0, 0><<<L_ / 128, 256, 0, stream>>>(hbuf, nullptr, nullptr, w_l2l2, b_l2l2, l2lb, 128);
        // pull-aggregation (no atomics, no memsets)
        gather_k<<<C_ / 4, 256, 0, stream>>>(cptr, cdegi, c_other, c_w, l_nxt, caggr, C_);
        gather_k<<<L_ / 4, 256, 0, stream>>>(lptr, ldegi, l_other, l_w, c_nxt, laggr, L_);
        // updates: c_new = [c,agg]@w_cu+b ; l_new = [l,agg,l2l]@w_lu+b
        gemm_k<0, 0><<<C_ / 128, 256, 0, stream>>>(c_cur, caggr, nullptr, w_cu, b_cu, c_nxt, 256);
        gemm_k<0, 0><<<L_ / 128, 256, 0, stream>>>(l_cur, laggr, l2lb, w_lu, b_lu, l_nxt, 384);
        float* tmp = l_cur; l_cur = l_nxt; l_nxt = tmp;
        tmp = c_cur; c_cur = c_nxt; c_nxt = tmp;
    }
    out_k<<<(L_ * D_) / 256, 256, 0, stream>>>(l_cur, d_out, L_ * D_, flags);
}

// Round 5
// 1060.703 us; speedup vs baseline: 2.9870x; 1.5657x over previous
//
#include <hip/hip_runtime.h>
#include <hip/hip_bf16.h>

#define D_ 128
#define L_ 65536
#define C_ 32768
#define E_ 262144

typedef __hip_bfloat16 bf16;
typedef __attribute__((ext_vector_type(8))) short short8;
typedef __attribute__((ext_vector_type(4))) float f32x4;

// flags[0] = 1 if float inputs are fp32 (else bf16); flags[1] = 1 if edge idx int32 (else int64)
__global__ void detect_k(const unsigned short* __restrict__ wmem,
                         const int* __restrict__ li, int* __restrict__ flags) {
    int t = blockIdx.x * 512 + threadIdx.x;
    if (t < 8192) {
        unsigned short h = wmem[2 * t];
        float v = __bfloat162float(*(const bf16*)&h);
        if (!(fabsf(v) < 0.5f)) atomicOr(&flags[0], 1);
    }
    if (t < 2048) {
        if (li[2 * t + 1] != 0) atomicOr(&flags[1], 1);
    }
}

__device__ __forceinline__ void split2(float v, unsigned short& h, unsigned short& l) {
    bf16 bh = __float2bfloat16(v);
    float fh = __bfloat162float(bh);
    bf16 bl = __float2bfloat16(v - fh);
    h = *(unsigned short*)&bh;
    l = *(unsigned short*)&bl;
}

__global__ void cvt_k(const void* __restrict__ s, float* __restrict__ d, int n,
                      const int* __restrict__ flags) {
    int i = blockIdx.x * 256 + threadIdx.x;
    if (i >= n) return;
    d[i] = flags[0] ? ((const float*)s)[i] : __bfloat162float(((const bf16*)s)[i]);
}

// Weight pre-split: src W[k][n] (K x 128) -> transposed bf16 hi/lo [n][k] (128 x K)
__global__ void cvtw_k(const void* __restrict__ src, unsigned short* __restrict__ hi,
                       unsigned short* __restrict__ lo, int K, const int* __restrict__ flags) {
    int i = blockIdx.x * 256 + threadIdx.x;
    if (i >= K * 128) return;
    int k = i >> 7, n = i & 127;
    float v = flags[0] ? ((const float*)src)[i] : __bfloat162float(((const bf16*)src)[i]);
    unsigned short h, l;
    split2(v, h, l);
    hi[n * K + k] = h;
    lo[n * K + k] = l;
}

__global__ void init_emb_k(const void* __restrict__ v, float* __restrict__ emb, int n,
                           const int* __restrict__ flags) {
    int i = blockIdx.x * 256 + threadIdx.x;
    if (i >= n) return;
    int j = i & (D_ - 1);
    emb[i] = flags[0] ? ((const float*)v)[j] : __bfloat162float(((const bf16*)v)[j]);
}

__global__ void fix_idx_k(const int* __restrict__ s, int* __restrict__ d, int n, int maxv,
                          const int* __restrict__ flags) {
    int i = blockIdx.x * 256 + threadIdx.x;
    if (i >= n) return;
    int v = flags[1] ? s[i] : s[2 * i];
    d[i] = min(max(v, 0), maxv - 1);
}

__global__ void degree_k(const int* __restrict__ li, const int* __restrict__ ci,
                         int* __restrict__ ld, int* __restrict__ cd) {
    int e = blockIdx.x * 256 + threadIdx.x;
    if (e < E_) {
        atomicAdd(&ld[li[e]], 1);
        atomicAdd(&cd[ci[e]], 1);
    }
}

__global__ void norm_k(const int* __restrict__ li, const int* __restrict__ ci,
                       const int* __restrict__ ld, const int* __restrict__ cd,
                       float* __restrict__ inv) {
    int e = blockIdx.x * 256 + threadIdx.x;
    if (e < E_) inv[e] = rsqrtf((float)ld[li[e]] * (float)cd[ci[e]]);
}

// --- two-level exclusive scan (tiles of 256) ---
__global__ void scan1_k(const int* __restrict__ in, int* __restrict__ out,
                        int* __restrict__ bsum, int n) {
    __shared__ int s[256];
    int i = blockIdx.x * 256 + threadIdx.x;
    int v = (i < n) ? in[i] : 0;
    s[threadIdx.x] = v;
    __syncthreads();
#pragma unroll
    for (int off = 1; off < 256; off <<= 1) {
        int t = (threadIdx.x >= off) ? s[threadIdx.x - off] : 0;
        __syncthreads();
        s[threadIdx.x] += t;
        __syncthreads();
    }
    if (i < n) out[i] = s[threadIdx.x] - v;  // exclusive
    if (threadIdx.x == 255) bsum[blockIdx.x] = s[255];
}

__global__ void scan2_k(int* __restrict__ b, int nb) {
    __shared__ int s[256];
    int v = (threadIdx.x < nb) ? b[threadIdx.x] : 0;
    s[threadIdx.x] = v;
    __syncthreads();
#pragma unroll
    for (int off = 1; off < 256; off <<= 1) {
        int t = (threadIdx.x >= off) ? s[threadIdx.x - off] : 0;
        __syncthreads();
        s[threadIdx.x] += t;
        __syncthreads();
    }
    if (threadIdx.x < nb) b[threadIdx.x] = s[threadIdx.x] - v;
}

__global__ void scan3_k(int* __restrict__ out, const int* __restrict__ bsum, int n) {
    int i = blockIdx.x * 256 + threadIdx.x;
    if (i < n) out[i] += bsum[blockIdx.x];
}

// CSR placement: write (other endpoint, edge weight) into each node's slot range.
__global__ void place_k(const int* __restrict__ li, const int* __restrict__ ci,
                        const float* __restrict__ inv,
                        int* __restrict__ lcur, int* __restrict__ ccur,
                        int* __restrict__ l_other, float* __restrict__ l_w,
                        int* __restrict__ c_other, float* __restrict__ c_w) {
    int e = blockIdx.x * 256 + threadIdx.x;
    if (e >= E_) return;
    int l = li[e], c = ci[e];
    float w = inv[e];
    int p = atomicAdd(&ccur[c], 1);
    c_other[p] = l; c_w[p] = w;
    int q = atomicAdd(&lcur[l], 1);
    l_other[q] = c; l_w[q] = w;
}

// Pull-aggregation: one wave per destination node, lanes own 2 of 128 features.
__global__ __launch_bounds__(256) void gather_k(
    const int* __restrict__ ptr, const int* __restrict__ deg,
    const int* __restrict__ other, const float* __restrict__ w,
    const float* __restrict__ msg, float* __restrict__ out, int n) {
    int node = (blockIdx.x * 256 + threadIdx.x) >> 6;
    int lane = threadIdx.x & 63;
    if (node >= n) return;
    int s = ptr[node], cnt = deg[node];
    float2 acc = {0.0f, 0.0f};
    for (int k = 0; k < cnt; k++) {
        int o = other[s + k];
        float ww = w[s + k];
        const float2 m = *(const float2*)&msg[o * D_ + 2 * lane];
        acc.x = fmaf(m.x, ww, acc.x);
        acc.y = fmaf(m.y, ww, acc.y);
    }
    *(float2*)&out[node * D_ + 2 * lane] = acc;
}

// out[N x 128] = act( concatK(A0,A1,A2)[N x K] @ W[K x 128] + bias )
// MFMA bf16x3: A,W split to bf16 hi/lo; acc += Ah*Bh + Ah*Bl + Al*Bh (fp32 AGPR acc).
// Block 256 thr = 4 waves (2x2), tile 128x128; wave tile 64x64 = 4x4 mfma_16x16x32 tiles.
// Verified layouts: A[m=lane&15][k=quad*8+j]; C/D col=lane&15,row=quad*4+reg.
// LDS rows padded to 40 ushorts (20-bank stride -> 2-way access = free).
template <int RELU, int SWAP>
__global__ __launch_bounds__(256, 2) void gemm_k(
    const float* __restrict__ A0, const float* __restrict__ A1, const float* __restrict__ A2,
    const unsigned short* __restrict__ WThi, const unsigned short* __restrict__ WTlo,
    const float* __restrict__ bias, float* __restrict__ out, int K) {
    __shared__ unsigned short a_hi[128][40], a_lo[128][40];  // [row][k]
    __shared__ unsigned short b_hi[128][40], b_lo[128][40];  // [col][k]
    const int t = threadIdx.x;
    const int br0 = blockIdx.x * 128;
    const int w = t >> 6, lane = t & 63;
    const int wr = w >> 1, wc = w & 1;
    const int quad = lane >> 4, cl = lane & 15;

    f32x4 acc[4][4];
#pragma unroll
    for (int i = 0; i < 4; i++)
#pragma unroll
        for (int j = 0; j < 4; j++) acc[i][j] = (f32x4){0.f, 0.f, 0.f, 0.f};

    for (int kt = 0; kt < K; kt += 32) {
        const float* As = (kt < 128) ? A0 : (kt < 256) ? A1 : A2;
        const int koff = kt & 127;
#pragma unroll
        for (int i = 0; i < 4; i++) {
            int f = t + 256 * i;
            int r = f >> 3, kq = f & 7;   // r: row (A) / col (W), kq: k-quad
            int gr = br0 + r;
            if (SWAP) gr ^= 1;
            const float4 v = *(const float4*)&As[(size_t)gr * D_ + koff + 4 * kq];
            unsigned short h0, l0, h1, l1, h2, l2, h3, l3;
            split2(v.x, h0, l0); split2(v.y, h1, l1);
            split2(v.z, h2, l2); split2(v.w, h3, l3);
            *(ushort4*)&a_hi[r][4 * kq] = make_ushort4(h0, h1, h2, h3);
            *(ushort4*)&a_lo[r][4 * kq] = make_ushort4(l0, l1, l2, l3);
            // W tile: pre-split transposed [n][k] -> straight coalesced copy
            *(ushort4*)&b_hi[r][4 * kq] = *(const ushort4*)&WThi[(size_t)r * K + kt + 4 * kq];
            *(ushort4*)&b_lo[r][4 * kq] = *(const ushort4*)&WTlo[(size_t)r * K + kt + 4 * kq];
        }
        __syncthreads();
        short8 af_h[4], af_l[4];
#pragma unroll
        for (int i = 0; i < 4; i++) {
            int row = 64 * wr + 16 * i + cl;
            af_h[i] = *(const short8*)&a_hi[row][quad * 8];
            af_l[i] = *(const short8*)&a_lo[row][quad * 8];
        }
#pragma unroll
        for (int j = 0; j < 4; j++) {
            int col = 64 * wc + 16 * j + cl;
            short8 bf_h = *(const short8*)&b_hi[col][quad * 8];
            short8 bf_l = *(const short8*)&b_lo[col][quad * 8];
#pragma unroll
            for (int i = 0; i < 4; i++) {
                acc[i][j] = __builtin_amdgcn_mfma_f32_16x16x32_bf16(af_h[i], bf_h, acc[i][j], 0, 0, 0);
                acc[i][j] = __builtin_amdgcn_mfma_f32_16x16x32_bf16(af_h[i], bf_l, acc[i][j], 0, 0, 0);
                acc[i][j] = __builtin_amdgcn_mfma_f32_16x16x32_bf16(af_l[i], bf_h, acc[i][j], 0, 0, 0);
            }
        }
        __syncthreads();
    }
    // epilogue: C/D layout col=lane&15, row=quad*4+reg
#pragma unroll
    for (int j = 0; j < 4; j++) {
        int col = 64 * wc + 16 * j + cl;
        float bv = bias[col];
#pragma unroll
        for (int i = 0; i < 4; i++) {
            int rbase = br0 + 64 * wr + 16 * i + quad * 4;
#pragma unroll
            for (int rg = 0; rg < 4; rg++) {
                float v = acc[i][j][rg] + bv;
                if (RELU) v = fmaxf(v, 0.0f);
                out[(size_t)(rbase + rg) * D_ + col] = v;
            }
        }
    }
}

__global__ void out_k(const float* __restrict__ s, void* __restrict__ d, int n,
                      const int* __restrict__ flags) {
    int i = blockIdx.x * 256 + threadIdx.x;
    if (i >= n) return;
    if (flags[0]) ((float*)d)[i] = s[i];
    else ((bf16*)d)[i] = __float2bfloat16(s[i]);
}

extern "C" void kernel_launch(void* const* d_in, const int* in_sizes, int n_in,
                              void* d_out, int out_size, void* d_ws, size_t ws_size,
                              hipStream_t stream) {
    const int* li_raw = (const int*)d_in[0];
    const int* ci_raw = (const int*)d_in[1];

    // ---- workspace layout ----
    float* ws = (float*)d_ws;
    float* lbuf0 = ws;                               // L*D
    float* lbuf1 = lbuf0 + (size_t)L_ * D_;          // L*D
    float* l2lb  = lbuf1 + (size_t)L_ * D_;          // L*D
    float* laggr = l2lb + (size_t)L_ * D_;           // L*D (aliased as MLP hidden buf)
    float* cbuf0 = laggr + (size_t)L_ * D_;          // C*D
    float* cbuf1 = cbuf0 + (size_t)C_ * D_;          // C*D
    float* caggr = cbuf1 + (size_t)C_ * D_;          // C*D
    float* invn  = caggr + (size_t)C_ * D_;          // E
    float* l_w   = invn + E_;                        // E
    float* c_w   = l_w + E_;                         // E
    float* bb    = c_w + E_;                         // 1024 bias floats
    unsigned short* wt_hi = (unsigned short*)(bb + 1024);   // 180224 ushorts
    unsigned short* wt_lo = wt_hi + 180224;                 // 180224 ushorts
    int*   li    = (int*)(wt_lo + 180224);           // E
    int*   ci    = li + E_;                          // E
    int*   l_other = ci + E_;                        // E
    int*   c_other = l_other + E_;                   // E
    int*   ldegi = c_other + E_;                     // L
    int*   cdegi = ldegi + L_;                       // C
    int*   lptr  = cdegi + C_;                       // L
    int*   cptr  = lptr + L_;                        // C
    int*   lcur  = cptr + C_;                        // L
    int*   ccur  = lcur + L_;                        // C
    int*   bsum  = ccur + C_;                        // 256 scratch for scans
    int*   flags = bsum + 256;                       // 2
    float* hbuf  = laggr;                            // alias: dead before gather writes laggr

    // split-weight offsets (elements) in wt_hi/wt_lo pools
    unsigned short* wt_l2c1_h = wt_hi + 0;      unsigned short* wt_l2c1_l = wt_lo + 0;
    unsigned short* wt_l2c2_h = wt_hi + 16384;  unsigned short* wt_l2c2_l = wt_lo + 16384;
    unsigned short* wt_c2l1_h = wt_hi + 32768;  unsigned short* wt_c2l1_l = wt_lo + 32768;
    unsigned short* wt_c2l2_h = wt_hi + 49152;  unsigned short* wt_c2l2_l = wt_lo + 49152;
    unsigned short* wt_l2l1_h = wt_hi + 65536;  unsigned short* wt_l2l1_l = wt_lo + 65536;
    unsigned short* wt_l2l2_h = wt_hi + 81920;  unsigned short* wt_l2l2_l = wt_lo + 81920;
    unsigned short* wt_cu_h   = wt_hi + 98304;  unsigned short* wt_cu_l   = wt_lo + 98304;
    unsigned short* wt_lu_h   = wt_hi + 131072; unsigned short* wt_lu_l   = wt_lo + 131072;
    float* b_l2c1 = bb + 0;   float* b_l2c2 = bb + 128;
    float* b_c2l1 = bb + 256; float* b_c2l2 = bb + 384;
    float* b_l2l1 = bb + 512; float* b_l2l2 = bb + 640;
    float* b_cu   = bb + 768; float* b_lu   = bb + 896;

    // --- dtype detection (device-side, graph-safe) ---
    hipMemsetAsync(flags, 0, 2 * sizeof(int), stream);
    detect_k<<<16, 512, 0, stream>>>((const unsigned short*)d_in[4], li_raw, flags);

    // --- index cleanup ---
    fix_idx_k<<<E_ / 256, 256, 0, stream>>>(li_raw, li, E_, L_, flags);
    fix_idx_k<<<E_ / 256, 256, 0, stream>>>(ci_raw, ci, E_, C_, flags);

    // --- weight split (transposed bf16 hi/lo) + bias conversion ---
    struct WJob { int idx; unsigned short* h; unsigned short* l; int K; };
    const WJob wjobs[8] = {
        {4, wt_l2c1_h, wt_l2c1_l, 128}, {6, wt_l2c2_h, wt_l2c2_l, 128},
        {8, wt_c2l1_h, wt_c2l1_l, 128}, {10, wt_c2l2_h, wt_c2l2_l, 128},
        {12, wt_l2l1_h, wt_l2l1_l, 128}, {14, wt_l2l2_h, wt_l2l2_l, 128},
        {16, wt_cu_h, wt_cu_l, 256}, {18, wt_lu_h, wt_lu_l, 384},
    };
    for (int j = 0; j < 8; j++)
        cvtw_k<<<(wjobs[j].K * 128) / 256, 256, 0, stream>>>(d_in[wjobs[j].idx], wjobs[j].h,
                                                             wjobs[j].l, wjobs[j].K, flags);
    struct BJob { int idx; float* dst; };
    const BJob bjobs[8] = {
        {5, b_l2c1}, {7, b_l2c2}, {9, b_c2l1}, {11, b_c2l2},
        {13, b_l2l1}, {15, b_l2l2}, {17, b_cu}, {19, b_lu},
    };
    for (int j = 0; j < 8; j++)
        cvt_k<<<1, 256, 0, stream>>>(d_in[bjobs[j].idx], bjobs[j].dst, 128, flags);

    // --- CSR build: degrees -> exclusive scan -> per-edge norm -> placement ---
    hipMemsetAsync(ldegi, 0, (size_t)(L_ + C_) * sizeof(int), stream);
    degree_k<<<E_ / 256, 256, 0, stream>>>(li, ci, ldegi, cdegi);

    scan1_k<<<L_ / 256, 256, 0, stream>>>(ldegi, lptr, bsum, L_);
    scan2_k<<<1, 256, 0, stream>>>(bsum, L_ / 256);
    scan3_k<<<L_ / 256, 256, 0, stream>>>(lptr, bsum, L_);
    scan1_k<<<C_ / 256, 256, 0, stream>>>(cdegi, cptr, bsum, C_);
    scan2_k<<<1, 256, 0, stream>>>(bsum, C_ / 256);
    scan3_k<<<C_ / 256, 256, 0, stream>>>(cptr, bsum, C_);

    norm_k<<<E_ / 256, 256, 0, stream>>>(li, ci, ldegi, cdegi, invn);

    hipMemcpyAsync(lcur, lptr, (size_t)L_ * sizeof(int), hipMemcpyDeviceToDevice, stream);
    hipMemcpyAsync(ccur, cptr, (size_t)C_ * sizeof(int), hipMemcpyDeviceToDevice, stream);
    place_k<<<E_ / 256, 256, 0, stream>>>(li, ci, invn, lcur, ccur,
                                          l_other, l_w, c_other, c_w);

    // --- broadcast-init embeddings ---
    init_emb_k<<<(L_ * D_) / 256, 256, 0, stream>>>(d_in[2], lbuf0, L_ * D_, flags);
    init_emb_k<<<(C_ * D_) / 256, 256, 0, stream>>>(d_in[3], cbuf0, C_ * D_, flags);

    float* l_cur = lbuf0; float* l_nxt = lbuf1;
    float* c_cur = cbuf0; float* c_nxt = cbuf1;

    for (int it = 0; it < 4; it++) {
        // node-level messages (hbuf==laggr is free during this phase)
        gemm_k<1, 0><<<L_ / 128, 256, 0, stream>>>(l_cur, nullptr, nullptr, wt_l2c1_h, wt_l2c1_l, b_l2c1, hbuf, 128);
        gemm_k<0, 0><<<L_ / 128, 256, 0, stream>>>(hbuf, nullptr, nullptr, wt_l2c2_h, wt_l2c2_l, b_l2c2, l_nxt, 128);
        gemm_k<1, 0><<<C_ / 128, 256, 0, stream>>>(c_cur, nullptr, nullptr, wt_c2l1_h, wt_c2l1_l, b_c2l1, hbuf, 128);
        gemm_k<0, 0><<<C_ / 128, 256, 0, stream>>>(hbuf, nullptr, nullptr, wt_c2l2_h, wt_c2l2_l, b_c2l2, c_nxt, 128);
        gemm_k<1, 1><<<L_ / 128, 256, 0, stream>>>(l_cur, nullptr, nullptr, wt_l2l1_h, wt_l2l1_l, b_l2l1, hbuf, 128);
        gemm_k<0, 0><<<L_ / 128, 256, 0, stream>>>(hbuf, nullptr, nullptr, wt_l2l2_h, wt_l2l2_l, b_l2l2, l2lb, 128);
        // pull-aggregation (no atomics, no memsets)
        gather_k<<<C_ / 4, 256, 0, stream>>>(cptr, cdegi, c_other, c_w, l_nxt, caggr, C_);
        gather_k<<<L_ / 4, 256, 0, stream>>>(lptr, ldegi, l_other, l_w, c_nxt, laggr, L_);
        // updates: c_new = [c,agg]@w_cu+b ; l_new = [l,agg,l2l]@w_lu+b
        gemm_k<0, 0><<<C_ / 128, 256, 0, stream>>>(c_cur, caggr, nullptr, wt_cu_h, wt_cu_l, b_cu, c_nxt, 256);
        gemm_k<0, 0><<<L_ / 128, 256, 0, stream>>>(l_cur, laggr, l2lb, wt_lu_h, wt_lu_l, b_lu, l_nxt, 384);
        float* tmp = l_cur; l_cur = l_nxt; l_nxt = tmp;
        tmp = c_cur; c_cur = c_nxt; c_nxt = tmp;
    }
    out_k<<<(L_ * D_) / 256, 256, 0, stream>>>(l_cur, d_out, L_ * D_, flags);
}

// Round 6
// 859.982 us; speedup vs baseline: 3.6842x; 1.2334x over previous
//
#include <hip/hip_runtime.h>
#include <hip/hip_bf16.h>

#define D_ 128
#define L_ 65536
#define C_ 32768
#define E_ 262144

typedef __hip_bfloat16 bf16;
typedef __attribute__((ext_vector_type(8))) short short8;
typedef __attribute__((ext_vector_type(4))) float f32x4;

// flags[0] = 1 if float inputs are fp32 (else bf16); flags[1] = 1 if edge idx int32 (else int64)
__global__ void detect_k(const unsigned short* __restrict__ wmem,
                         const int* __restrict__ li, int* __restrict__ flags) {
    int t = blockIdx.x * 512 + threadIdx.x;
    if (t < 8192) {
        unsigned short h = wmem[2 * t];
        float v = __bfloat162float(*(const bf16*)&h);
        if (!(fabsf(v) < 0.5f)) atomicOr(&flags[0], 1);
    }
    if (t < 2048) {
        if (li[2 * t + 1] != 0) atomicOr(&flags[1], 1);
    }
}

__device__ __forceinline__ void split2(float v, unsigned short& h, unsigned short& l) {
    bf16 bh = __float2bfloat16(v);
    float fh = __bfloat162float(bh);
    bf16 bl = __float2bfloat16(v - fh);
    h = *(unsigned short*)&bh;
    l = *(unsigned short*)&bl;
}

__device__ __forceinline__ float ldf(const void* s, int i, int isf32) {
    return isf32 ? ((const float*)s)[i] : __bfloat162float(((const bf16*)s)[i]);
}

// All 8 weight matrices: src W[k][n] -> transposed bf16 hi/lo [n][k], packed pool.
__global__ void cvtw_all_k(const void* s0, const void* s1, const void* s2, const void* s3,
                           const void* s4, const void* s5, const void* s6, const void* s7,
                           unsigned short* __restrict__ hi, unsigned short* __restrict__ lo,
                           const int* __restrict__ flags) {
    int i = blockIdx.x * 256 + threadIdx.x;  // packed element id, total 180224
    const void* src; int K, base;
    if      (i <  16384) { src = s0; K = 128; base = 0; }
    else if (i <  32768) { src = s1; K = 128; base = 16384; }
    else if (i <  49152) { src = s2; K = 128; base = 32768; }
    else if (i <  65536) { src = s3; K = 128; base = 49152; }
    else if (i <  81920) { src = s4; K = 128; base = 65536; }
    else if (i <  98304) { src = s5; K = 128; base = 81920; }
    else if (i < 131072) { src = s6; K = 256; base = 98304; }
    else                 { src = s7; K = 384; base = 131072; }
    int e = i - base;
    int k = e >> 7, n = e & 127;
    float v = ldf(src, e, flags[0]);
    unsigned short h, l;
    split2(v, h, l);
    hi[base + n * K + k] = h;
    lo[base + n * K + k] = l;
}

__global__ void cvtb_all_k(const void* s0, const void* s1, const void* s2, const void* s3,
                           const void* s4, const void* s5, const void* s6, const void* s7,
                           float* __restrict__ bb, const int* __restrict__ flags) {
    int i = blockIdx.x * 256 + threadIdx.x;  // 1024 total
    if (i >= 1024) return;
    const void* src;
    switch (i >> 7) {
        case 0: src = s0; break; case 1: src = s1; break;
        case 2: src = s2; break; case 3: src = s3; break;
        case 4: src = s4; break; case 5: src = s5; break;
        case 6: src = s6; break; default: src = s7; break;
    }
    bb[i] = ldf(src, i & 127, flags[0]);
}

__global__ void init2_k(const void* __restrict__ lv, const void* __restrict__ cv,
                        float* __restrict__ lemb, float* __restrict__ cemb,
                        const int* __restrict__ flags) {
    int i = blockIdx.x * 256 + threadIdx.x;
    int isf = flags[0];
    if (i < L_ * D_) lemb[i] = ldf(lv, i & (D_ - 1), isf);
    else             cemb[i - L_ * D_] = ldf(cv, i & (D_ - 1), isf);
}

__global__ void fix_idx2_k(const int* __restrict__ ls, const int* __restrict__ cs,
                           int* __restrict__ ld, int* __restrict__ cd,
                           const int* __restrict__ flags) {
    int i = blockIdx.x * 256 + threadIdx.x;
    int is32 = flags[1];
    if (i < E_) {
        int v = is32 ? ls[i] : ls[2 * i];
        ld[i] = min(max(v, 0), L_ - 1);
    } else {
        int j = i - E_;
        int v = is32 ? cs[j] : cs[2 * j];
        cd[j] = min(max(v, 0), C_ - 1);
    }
}

__global__ void degree_k(const int* __restrict__ li, const int* __restrict__ ci,
                         int* __restrict__ ld, int* __restrict__ cd) {
    int e = blockIdx.x * 256 + threadIdx.x;
    if (e < E_) {
        atomicAdd(&ld[li[e]], 1);
        atomicAdd(&cd[ci[e]], 1);
    }
}

__global__ void norm_k(const int* __restrict__ li, const int* __restrict__ ci,
                       const int* __restrict__ ld, const int* __restrict__ cd,
                       float* __restrict__ inv) {
    int e = blockIdx.x * 256 + threadIdx.x;
    if (e < E_) inv[e] = rsqrtf((float)ld[li[e]] * (float)cd[ci[e]]);
}

// --- two-level exclusive scan (tiles of 256) ---
__global__ void scan1_k(const int* __restrict__ in, int* __restrict__ out,
                        int* __restrict__ bsum, int n) {
    __shared__ int s[256];
    int i = blockIdx.x * 256 + threadIdx.x;
    int v = (i < n) ? in[i] : 0;
    s[threadIdx.x] = v;
    __syncthreads();
#pragma unroll
    for (int off = 1; off < 256; off <<= 1) {
        int t = (threadIdx.x >= off) ? s[threadIdx.x - off] : 0;
        __syncthreads();
        s[threadIdx.x] += t;
        __syncthreads();
    }
    if (i < n) out[i] = s[threadIdx.x] - v;  // exclusive
    if (threadIdx.x == 255) bsum[blockIdx.x] = s[255];
}

__global__ void scan2_k(int* __restrict__ b, int nb) {
    __shared__ int s[256];
    int v = (threadIdx.x < nb) ? b[threadIdx.x] : 0;
    s[threadIdx.x] = v;
    __syncthreads();
#pragma unroll
    for (int off = 1; off < 256; off <<= 1) {
        int t = (threadIdx.x >= off) ? s[threadIdx.x - off] : 0;
        __syncthreads();
        s[threadIdx.x] += t;
        __syncthreads();
    }
    if (threadIdx.x < nb) b[threadIdx.x] = s[threadIdx.x] - v;
}

// adds block sums and also initializes the placement cursor array
__global__ void scan3_k(int* __restrict__ out, const int* __restrict__ bsum,
                        int* __restrict__ cur, int n) {
    int i = blockIdx.x * 256 + threadIdx.x;
    if (i < n) {
        int v = out[i] + bsum[blockIdx.x];
        out[i] = v;
        cur[i] = v;
    }
}

// CSR placement: write (other endpoint, edge weight) into each node's slot range.
__global__ void place_k(const int* __restrict__ li, const int* __restrict__ ci,
                        const float* __restrict__ inv,
                        int* __restrict__ lcur, int* __restrict__ ccur,
                        int* __restrict__ l_other, float* __restrict__ l_w,
                        int* __restrict__ c_other, float* __restrict__ c_w) {
    int e = blockIdx.x * 256 + threadIdx.x;
    if (e >= E_) return;
    int l = li[e], c = ci[e];
    float w = inv[e];
    int p = atomicAdd(&ccur[c], 1);
    c_other[p] = l; c_w[p] = w;
    int q = atomicAdd(&lcur[l], 1);
    l_other[q] = c; l_w[q] = w;
}

// Pull-aggregation: one wave per destination node; 2-way unroll keeps two
// independent row loads in flight (halves the index->row latency chain).
__global__ __launch_bounds__(256) void gather_k(
    const int* __restrict__ ptr, const int* __restrict__ deg,
    const int* __restrict__ other, const float* __restrict__ w,
    const float* __restrict__ msg, float* __restrict__ out, int n) {
    int node = (blockIdx.x * 256 + threadIdx.x) >> 6;
    int lane = threadIdx.x & 63;
    if (node >= n) return;
    int s = ptr[node], cnt = deg[node];
    float2 a0 = {0.f, 0.f}, a1 = {0.f, 0.f};
    int k = 0;
    for (; k + 2 <= cnt; k += 2) {
        int o0 = other[s + k], o1 = other[s + k + 1];
        float w0 = w[s + k], w1 = w[s + k + 1];
        const float2 m0 = *(const float2*)&msg[(size_t)o0 * D_ + 2 * lane];
        const float2 m1 = *(const float2*)&msg[(size_t)o1 * D_ + 2 * lane];
        a0.x = fmaf(m0.x, w0, a0.x); a0.y = fmaf(m0.y, w0, a0.y);
        a1.x = fmaf(m1.x, w1, a1.x); a1.y = fmaf(m1.y, w1, a1.y);
    }
    if (k < cnt) {
        int o = other[s + k];
        float ww = w[s + k];
        const float2 m = *(const float2*)&msg[(size_t)o * D_ + 2 * lane];
        a0.x = fmaf(m.x, ww, a0.x); a0.y = fmaf(m.y, ww, a0.y);
    }
    a0.x += a1.x; a0.y += a1.y;
    *(float2*)&out[(size_t)node * D_ + 2 * lane] = a0;
}

// ---------- fused 2-layer MLP: out = relu(A@W1+b1)@W2 + b2  (bf16x3 MFMA) ----------
// Phase 1: A (split on the fly) + W1 k-tiles in LDS (proven round-5 path).
// h -> bias+relu -> split -> LDS (XOR-swizzled [128][128] hi/lo, 64 KB; fragment
// reads 2-way bank = free). Phase 2: B-fragments streamed from global W2T (L2-hot,
// mapping byte-identical to the LDS path). One kernel, no HBM hidden round-trip.
template <int SWAP>
__global__ __launch_bounds__(256, 2) void mlp_k(
    const float* __restrict__ A,
    const unsigned short* __restrict__ W1h, const unsigned short* __restrict__ W1l,
    const float* __restrict__ b1v,
    const unsigned short* __restrict__ W2h, const unsigned short* __restrict__ W2l,
    const float* __restrict__ b2v, float* __restrict__ out) {
    __shared__ char smem[65536];
    unsigned short (*a_hi)[40] = (unsigned short(*)[40])(smem);
    unsigned short (*a_lo)[40] = (unsigned short(*)[40])(smem + 10240);
    unsigned short (*b_hi)[40] = (unsigned short(*)[40])(smem + 20480);
    unsigned short (*b_lo)[40] = (unsigned short(*)[40])(smem + 30720);
    unsigned short* h_hi = (unsigned short*)(smem);          // phase 2 (aliases tiles)
    unsigned short* h_lo = (unsigned short*)(smem + 32768);

    const int t = threadIdx.x;
    const int br0 = blockIdx.x * 128;
    const int w = t >> 6, lane = t & 63;
    const int wr = w >> 1, wc = w & 1;
    const int quad = lane >> 4, cl = lane & 15;

    f32x4 acc[4][4];
#pragma unroll
    for (int i = 0; i < 4; i++)
#pragma unroll
        for (int j = 0; j < 4; j++) acc[i][j] = (f32x4){0.f, 0.f, 0.f, 0.f};

    // ---- phase 1: h = A @ W1 ----
    for (int kt = 0; kt < 128; kt += 32) {
#pragma unroll
        for (int i = 0; i < 4; i++) {
            int f = t + 256 * i;
            int r = f >> 3, kq = f & 7;
            int gr = br0 + r;
            if (SWAP) gr ^= 1;
            const float4 v = *(const float4*)&A[(size_t)gr * D_ + kt + 4 * kq];
            unsigned short h0, l0, h1, l1, h2, l2, h3, l3;
            split2(v.x, h0, l0); split2(v.y, h1, l1);
            split2(v.z, h2, l2); split2(v.w, h3, l3);
            *(ushort4*)&a_hi[r][4 * kq] = make_ushort4(h0, h1, h2, h3);
            *(ushort4*)&a_lo[r][4 * kq] = make_ushort4(l0, l1, l2, l3);
            *(ushort4*)&b_hi[r][4 * kq] = *(const ushort4*)&W1h[(size_t)r * 128 + kt + 4 * kq];
            *(ushort4*)&b_lo[r][4 * kq] = *(const ushort4*)&W1l[(size_t)r * 128 + kt + 4 * kq];
        }
        __syncthreads();
        short8 af_h[4], af_l[4];
#pragma unroll
        for (int i = 0; i < 4; i++) {
            int row = 64 * wr + 16 * i + cl;
            af_h[i] = *(const short8*)&a_hi[row][quad * 8];
            af_l[i] = *(const short8*)&a_lo[row][quad * 8];
        }
#pragma unroll
        for (int j = 0; j < 4; j++) {
            int col = 64 * wc + 16 * j + cl;
            short8 bf_h = *(const short8*)&b_hi[col][quad * 8];
            short8 bf_l = *(const short8*)&b_lo[col][quad * 8];
#pragma unroll
            for (int i = 0; i < 4; i++) {
                acc[i][j] = __builtin_amdgcn_mfma_f32_16x16x32_bf16(af_h[i], bf_h, acc[i][j], 0, 0, 0);
                acc[i][j] = __builtin_amdgcn_mfma_f32_16x16x32_bf16(af_h[i], bf_l, acc[i][j], 0, 0, 0);
                acc[i][j] = __builtin_amdgcn_mfma_f32_16x16x32_bf16(af_l[i], bf_h, acc[i][j], 0, 0, 0);
            }
        }
        __syncthreads();
    }
    // h epilogue: bias + relu + split -> swizzled LDS. C/D: col=cl, row=quad*4+reg.
#pragma unroll
    for (int j = 0; j < 4; j++) {
        int col = 64 * wc + 16 * j + cl;  // hidden index k2
        float bv = b1v[col];
        int g = col >> 3, go = col & 7;
#pragma unroll
        for (int i = 0; i < 4; i++) {
            int rloc = 64 * wr + 16 * i + quad * 4;
#pragma unroll
            for (int rg = 0; rg < 4; rg++) {
                float v = fmaxf(acc[i][j][rg] + bv, 0.0f);
                unsigned short hh, ll;
                split2(v, hh, ll);
                int r = rloc + rg;
                int off = r * 128 + ((g ^ (r & 15)) << 3) + go;
                h_hi[off] = hh;
                h_lo[off] = ll;
            }
        }
    }
    __syncthreads();
    // ---- phase 2: out = h @ W2 + b2 (B-fragments from global) ----
#pragma unroll
    for (int i = 0; i < 4; i++)
#pragma unroll
        for (int j = 0; j < 4; j++) acc[i][j] = (f32x4){0.f, 0.f, 0.f, 0.f};

    for (int kt = 0; kt < 128; kt += 32) {
        short8 af_h[4], af_l[4];
        int gbase = (kt >> 3) + quad;
#pragma unroll
        for (int i = 0; i < 4; i++) {
            int r = 64 * wr + 16 * i + cl;  // r&15 == cl
            int off = r * 128 + ((gbase ^ cl) << 3);
            af_h[i] = *(const short8*)&h_hi[off];
            af_l[i] = *(const short8*)&h_lo[off];
        }
#pragma unroll
        for (int j = 0; j < 4; j++) {
            int col = 64 * wc + 16 * j + cl;
            const short8 bf_h = *(const short8*)&W2h[(size_t)col * 128 + kt + quad * 8];
            const short8 bf_l = *(const short8*)&W2l[(size_t)col * 128 + kt + quad * 8];
#pragma unroll
            for (int i = 0; i < 4; i++) {
                acc[i][j] = __builtin_amdgcn_mfma_f32_16x16x32_bf16(af_h[i], bf_h, acc[i][j], 0, 0, 0);
                acc[i][j] = __builtin_amdgcn_mfma_f32_16x16x32_bf16(af_h[i], bf_l, acc[i][j], 0, 0, 0);
                acc[i][j] = __builtin_amdgcn_mfma_f32_16x16x32_bf16(af_l[i], bf_h, acc[i][j], 0, 0, 0);
            }
        }
    }
#pragma unroll
    for (int j = 0; j < 4; j++) {
        int col = 64 * wc + 16 * j + cl;
        float bv = b2v[col];
#pragma unroll
        for (int i = 0; i < 4; i++) {
            int rbase = br0 + 64 * wr + 16 * i + quad * 4;
#pragma unroll
            for (int rg = 0; rg < 4; rg++)
                out[(size_t)(rbase + rg) * D_ + col] = acc[i][j][rg] + bv;
        }
    }
}

// Single-layer concat GEMM (round-5 proven path) for the update layers.
template <int RELU, int SWAP>
__global__ __launch_bounds__(256, 2) void gemm_k(
    const float* __restrict__ A0, const float* __restrict__ A1, const float* __restrict__ A2,
    const unsigned short* __restrict__ WThi, const unsigned short* __restrict__ WTlo,
    const float* __restrict__ bias, float* __restrict__ out, int K) {
    __shared__ unsigned short a_hi[128][40], a_lo[128][40];
    __shared__ unsigned short b_hi[128][40], b_lo[128][40];
    const int t = threadIdx.x;
    const int br0 = blockIdx.x * 128;
    const int w = t >> 6, lane = t & 63;
    const int wr = w >> 1, wc = w & 1;
    const int quad = lane >> 4, cl = lane & 15;

    f32x4 acc[4][4];
#pragma unroll
    for (int i = 0; i < 4; i++)
#pragma unroll
        for (int j = 0; j < 4; j++) acc[i][j] = (f32x4){0.f, 0.f, 0.f, 0.f};

    for (int kt = 0; kt < K; kt += 32) {
        const float* As = (kt < 128) ? A0 : (kt < 256) ? A1 : A2;
        const int koff = kt & 127;
#pragma unroll
        for (int i = 0; i < 4; i++) {
            int f = t + 256 * i;
            int r = f >> 3, kq = f & 7;
            int gr = br0 + r;
            if (SWAP) gr ^= 1;
            const float4 v = *(const float4*)&As[(size_t)gr * D_ + koff + 4 * kq];
            unsigned short h0, l0, h1, l1, h2, l2, h3, l3;
            split2(v.x, h0, l0); split2(v.y, h1, l1);
            split2(v.z, h2, l2); split2(v.w, h3, l3);
            *(ushort4*)&a_hi[r][4 * kq] = make_ushort4(h0, h1, h2, h3);
            *(ushort4*)&a_lo[r][4 * kq] = make_ushort4(l0, l1, l2, l3);
            *(ushort4*)&b_hi[r][4 * kq] = *(const ushort4*)&WThi[(size_t)r * K + kt + 4 * kq];
            *(ushort4*)&b_lo[r][4 * kq] = *(const ushort4*)&WTlo[(size_t)r * K + kt + 4 * kq];
        }
        __syncthreads();
        short8 af_h[4], af_l[4];
#pragma unroll
        for (int i = 0; i < 4; i++) {
            int row = 64 * wr + 16 * i + cl;
            af_h[i] = *(const short8*)&a_hi[row][quad * 8];
            af_l[i] = *(const short8*)&a_lo[row][quad * 8];
        }
#pragma unroll
        for (int j = 0; j < 4; j++) {
            int col = 64 * wc + 16 * j + cl;
            short8 bf_h = *(const short8*)&b_hi[col][quad * 8];
            short8 bf_l = *(const short8*)&b_lo[col][quad * 8];
#pragma unroll
            for (int i = 0; i < 4; i++) {
                acc[i][j] = __builtin_amdgcn_mfma_f32_16x16x32_bf16(af_h[i], bf_h, acc[i][j], 0, 0, 0);
                acc[i][j] = __builtin_amdgcn_mfma_f32_16x16x32_bf16(af_h[i], bf_l, acc[i][j], 0, 0, 0);
                acc[i][j] = __builtin_amdgcn_mfma_f32_16x16x32_bf16(af_l[i], bf_h, acc[i][j], 0, 0, 0);
            }
        }
        __syncthreads();
    }
#pragma unroll
    for (int j = 0; j < 4; j++) {
        int col = 64 * wc + 16 * j + cl;
        float bv = bias[col];
#pragma unroll
        for (int i = 0; i < 4; i++) {
            int rbase = br0 + 64 * wr + 16 * i + quad * 4;
#pragma unroll
            for (int rg = 0; rg < 4; rg++) {
                float v = acc[i][j][rg] + bv;
                if (RELU) v = fmaxf(v, 0.0f);
                out[(size_t)(rbase + rg) * D_ + col] = v;
            }
        }
    }
}

__global__ void out_k(const float* __restrict__ s, void* __restrict__ d, int n,
                      const int* __restrict__ flags) {
    int i = blockIdx.x * 256 + threadIdx.x;
    if (i >= n) return;
    if (flags[0]) ((float*)d)[i] = s[i];
    else ((bf16*)d)[i] = __float2bfloat16(s[i]);
}

extern "C" void kernel_launch(void* const* d_in, const int* in_sizes, int n_in,
                              void* d_out, int out_size, void* d_ws, size_t ws_size,
                              hipStream_t stream) {
    const int* li_raw = (const int*)d_in[0];
    const int* ci_raw = (const int*)d_in[1];

    // ---- workspace layout ----
    float* ws = (float*)d_ws;
    float* lbuf0 = ws;                               // L*D
    float* lbuf1 = lbuf0 + (size_t)L_ * D_;          // L*D
    float* l2lb  = lbuf1 + (size_t)L_ * D_;          // L*D
    float* laggr = l2lb + (size_t)L_ * D_;           // L*D
    float* cbuf0 = laggr + (size_t)L_ * D_;          // C*D
    float* cbuf1 = cbuf0 + (size_t)C_ * D_;          // C*D
    float* caggr = cbuf1 + (size_t)C_ * D_;          // C*D
    float* invn  = caggr + (size_t)C_ * D_;          // E
    float* l_w   = invn + E_;                        // E
    float* c_w   = l_w + E_;                         // E
    float* bb    = c_w + E_;                         // 1024 bias floats
    unsigned short* wt_hi = (unsigned short*)(bb + 1024);   // 180224 ushorts
    unsigned short* wt_lo = wt_hi + 180224;                 // 180224 ushorts
    int*   li    = (int*)(wt_lo + 180224);           // E
    int*   ci    = li + E_;                          // E
    int*   l_other = ci + E_;                        // E
    int*   c_other = l_other + E_;                   // E
    int*   ldegi = c_other + E_;                     // L
    int*   cdegi = ldegi + L_;                       // C
    int*   lptr  = cdegi + C_;                       // L
    int*   cptr  = lptr + L_;                        // C
    int*   lcur  = cptr + C_;                        // L
    int*   ccur  = lcur + L_;                        // C
    int*   bsum  = ccur + C_;                        // 256 scratch for scans
    int*   flags = bsum + 256;                       // 2

    unsigned short* wt_l2c1_h = wt_hi + 0;      unsigned short* wt_l2c1_l = wt_lo + 0;
    unsigned short* wt_l2c2_h = wt_hi + 16384;  unsigned short* wt_l2c2_l = wt_lo + 16384;
    unsigned short* wt_c2l1_h = wt_hi + 32768;  unsigned short* wt_c2l1_l = wt_lo + 32768;
    unsigned short* wt_c2l2_h = wt_hi + 49152;  unsigned short* wt_c2l2_l = wt_lo + 49152;
    unsigned short* wt_l2l1_h = wt_hi + 65536;  unsigned short* wt_l2l1_l = wt_lo + 65536;
    unsigned short* wt_l2l2_h = wt_hi + 81920;  unsigned short* wt_l2l2_l = wt_lo + 81920;
    unsigned short* wt_cu_h   = wt_hi + 98304;  unsigned short* wt_cu_l   = wt_lo + 98304;
    unsigned short* wt_lu_h   = wt_hi + 131072; unsigned short* wt_lu_l   = wt_lo + 131072;
    float* b_l2c1 = bb + 0;   float* b_l2c2 = bb + 128;
    float* b_c2l1 = bb + 256; float* b_c2l2 = bb + 384;
    float* b_l2l1 = bb + 512; float* b_l2l2 = bb + 640;
    float* b_cu   = bb + 768; float* b_lu   = bb + 896;

    // --- dtype detection (device-side, graph-safe) ---
    hipMemsetAsync(flags, 0, 2 * sizeof(int), stream);
    detect_k<<<16, 512, 0, stream>>>((const unsigned short*)d_in[4], li_raw, flags);

    // --- index cleanup (both lists, one launch) ---
    fix_idx2_k<<<2 * E_ / 256, 256, 0, stream>>>(li_raw, ci_raw, li, ci, flags);

    // --- weight split + bias conversion (one launch each) ---
    cvtw_all_k<<<704, 256, 0, stream>>>(d_in[4], d_in[6], d_in[8], d_in[10], d_in[12],
                                        d_in[14], d_in[16], d_in[18], wt_hi, wt_lo, flags);
    cvtb_all_k<<<4, 256, 0, stream>>>(d_in[5], d_in[7], d_in[9], d_in[11], d_in[13],
                                      d_in[15], d_in[17], d_in[19], bb, flags);

    // --- CSR build ---
    hipMemsetAsync(ldegi, 0, (size_t)(L_ + C_) * sizeof(int), stream);
    degree_k<<<E_ / 256, 256, 0, stream>>>(li, ci, ldegi, cdegi);
    scan1_k<<<L_ / 256, 256, 0, stream>>>(ldegi, lptr, bsum, L_);
    scan2_k<<<1, 256, 0, stream>>>(bsum, L_ / 256);
    scan3_k<<<L_ / 256, 256, 0, stream>>>(lptr, bsum, lcur, L_);
    scan1_k<<<C_ / 256, 256, 0, stream>>>(cdegi, cptr, bsum, C_);
    scan2_k<<<1, 256, 0, stream>>>(bsum, C_ / 256);
    scan3_k<<<C_ / 256, 256, 0, stream>>>(cptr, bsum, ccur, C_);
    norm_k<<<E_ / 256, 256, 0, stream>>>(li, ci, ldegi, cdegi, invn);
    place_k<<<E_ / 256, 256, 0, stream>>>(li, ci, invn, lcur, ccur,
                                          l_other, l_w, c_other, c_w);

    // --- broadcast-init embeddings (one launch) ---
    init2_k<<<(L_ + C_) * D_ / 256, 256, 0, stream>>>(d_in[2], d_in[3], lbuf0, cbuf0, flags);

    float* l_cur = lbuf0; float* l_nxt = lbuf1;
    float* c_cur = cbuf0; float* c_nxt = cbuf1;

    for (int it = 0; it < 4; it++) {
        // fused 2-layer message MLPs
        mlp_k<0><<<L_ / 128, 256, 0, stream>>>(l_cur, wt_l2c1_h, wt_l2c1_l, b_l2c1,
                                               wt_l2c2_h, wt_l2c2_l, b_l2c2, l_nxt);
        mlp_k<0><<<C_ / 128, 256, 0, stream>>>(c_cur, wt_c2l1_h, wt_c2l1_l, b_c2l1,
                                               wt_c2l2_h, wt_c2l2_l, b_c2l2, c_nxt);
        mlp_k<1><<<L_ / 128, 256, 0, stream>>>(l_cur, wt_l2l1_h, wt_l2l1_l, b_l2l1,
                                               wt_l2l2_h, wt_l2l2_l, b_l2l2, l2lb);
        // pull-aggregation
        gather_k<<<C_ / 4, 256, 0, stream>>>(cptr, cdegi, c_other, c_w, l_nxt, caggr, C_);
        gather_k<<<L_ / 4, 256, 0, stream>>>(lptr, ldegi, l_other, l_w, c_nxt, laggr, L_);
        // updates: c_new = [c,agg]@w_cu+b ; l_new = [l,agg,l2l]@w_lu+b
        gemm_k<0, 0><<<C_ / 128, 256, 0, stream>>>(c_cur, caggr, nullptr, wt_cu_h, wt_cu_l,
                                                   b_cu, c_nxt, 256);
        gemm_k<0, 0><<<L_ / 128, 256, 0, stream>>>(l_cur, laggr, l2lb, wt_lu_h, wt_lu_l,
                                                   b_lu, l_nxt, 384);
        float* tmp = l_cur; l_cur = l_nxt; l_nxt = tmp;
        tmp = c_cur; c_cur = c_nxt; c_nxt = tmp;
    }
    out_k<<<(L_ * D_) / 256, 256, 0, stream>>>(l_cur, d_out, L_ * D_, flags);
}

// Round 7
// 695.370 us; speedup vs baseline: 4.5563x; 1.2367x over previous
//
#include <hip/hip_runtime.h>
#include <hip/hip_bf16.h>

#define D_ 128
#define L_ 65536
#define C_ 32768
#define E_ 262144

typedef __hip_bfloat16 bf16;
typedef __attribute__((ext_vector_type(8))) short short8;
typedef __attribute__((ext_vector_type(4))) float f32x4;

// flags[0] = 1 if float inputs are fp32 (else bf16); flags[1] = 1 if edge idx int32 (else int64)
__global__ void detect_k(const unsigned short* __restrict__ wmem,
                         const int* __restrict__ li, int* __restrict__ flags) {
    int t = blockIdx.x * 512 + threadIdx.x;
    if (t < 8192) {
        unsigned short h = wmem[2 * t];
        float v = __bfloat162float(*(const bf16*)&h);
        if (!(fabsf(v) < 0.5f)) atomicOr(&flags[0], 1);
    }
    if (t < 2048) {
        if (li[2 * t + 1] != 0) atomicOr(&flags[1], 1);
    }
}

__device__ __forceinline__ void split2(float v, unsigned short& h, unsigned short& l) {
    bf16 bh = __float2bfloat16(v);
    float fh = __bfloat162float(bh);
    bf16 bl = __float2bfloat16(v - fh);
    h = *(unsigned short*)&bh;
    l = *(unsigned short*)&bl;
}

__device__ __forceinline__ float ldf(const void* s, int i, int isf32) {
    return isf32 ? ((const float*)s)[i] : __bfloat162float(((const bf16*)s)[i]);
}

// index fix (int32/int64, clamp) + degree count, both sides in one launch
__global__ void fixdeg_k(const int* __restrict__ ls, const int* __restrict__ cs,
                         int* __restrict__ ld_idx, int* __restrict__ cd_idx,
                         int* __restrict__ ldeg, int* __restrict__ cdeg,
                         const int* __restrict__ flags) {
    int i = blockIdx.x * 256 + threadIdx.x;
    int is32 = flags[1];
    if (i < E_) {
        int v = is32 ? ls[i] : ls[2 * i];
        v = min(max(v, 0), L_ - 1);
        ld_idx[i] = v;
        atomicAdd(&ldeg[v], 1);
    } else {
        int j = i - E_;
        int v = is32 ? cs[j] : cs[2 * j];
        v = min(max(v, 0), C_ - 1);
        cd_idx[j] = v;
        atomicAdd(&cdeg[v], 1);
    }
}

// weights: W[k][n] -> transposed bf16 hi/lo [n][k] packed pool; tail: biases -> fp32
__global__ void cvtwb_k(const void* s0, const void* s1, const void* s2, const void* s3,
                        const void* s4, const void* s5, const void* s6, const void* s7,
                        const void* t0, const void* t1, const void* t2, const void* t3,
                        const void* t4, const void* t5, const void* t6, const void* t7,
                        unsigned short* __restrict__ hi, unsigned short* __restrict__ lo,
                        float* __restrict__ bb, const int* __restrict__ flags) {
    int i = blockIdx.x * 256 + threadIdx.x;  // 181248 total
    int isf = flags[0];
    if (i >= 180224) {
        int j = i - 180224;  // 0..1023
        const void* src;
        switch (j >> 7) {
            case 0: src = t0; break; case 1: src = t1; break;
            case 2: src = t2; break; case 3: src = t3; break;
            case 4: src = t4; break; case 5: src = t5; break;
            case 6: src = t6; break; default: src = t7; break;
        }
        bb[j] = ldf(src, j & 127, isf);
        return;
    }
    const void* src; int K, base;
    if      (i <  16384) { src = s0; K = 128; base = 0; }
    else if (i <  32768) { src = s1; K = 128; base = 16384; }
    else if (i <  49152) { src = s2; K = 128; base = 32768; }
    else if (i <  65536) { src = s3; K = 128; base = 49152; }
    else if (i <  81920) { src = s4; K = 128; base = 65536; }
    else if (i <  98304) { src = s5; K = 128; base = 81920; }
    else if (i < 131072) { src = s6; K = 256; base = 98304; }
    else                 { src = s7; K = 384; base = 131072; }
    int e = i - base;
    int k = e >> 7, n = e & 127;
    float v = ldf(src, e, isf);
    unsigned short h, l;
    split2(v, h, l);
    hi[base + n * K + k] = h;
    lo[base + n * K + k] = l;
}

__global__ void init2_k(const void* __restrict__ lv, const void* __restrict__ cv,
                        float* __restrict__ lemb, float* __restrict__ cemb,
                        const int* __restrict__ flags) {
    int i = blockIdx.x * 256 + threadIdx.x;
    int isf = flags[0];
    if (i < L_ * D_) lemb[i] = ldf(lv, i & (D_ - 1), isf);
    else             cemb[i - L_ * D_] = ldf(cv, i & (D_ - 1), isf);
}

// --- two-level exclusive scans, both sides fused ---
__global__ void scan1b_k(const int* __restrict__ ldeg, const int* __restrict__ cdeg,
                         int* __restrict__ lout, int* __restrict__ cout,
                         int* __restrict__ bsumL, int* __restrict__ bsumC) {
    __shared__ int s[256];
    const int* in; int* out; int* bs; int tile;
    if (blockIdx.x < 256) { in = ldeg; out = lout; bs = bsumL; tile = blockIdx.x; }
    else                  { in = cdeg; out = cout; bs = bsumC; tile = blockIdx.x - 256; }
    int i = tile * 256 + threadIdx.x;
    int v = in[i];
    s[threadIdx.x] = v;
    __syncthreads();
#pragma unroll
    for (int off = 1; off < 256; off <<= 1) {
        int t = (threadIdx.x >= off) ? s[threadIdx.x - off] : 0;
        __syncthreads();
        s[threadIdx.x] += t;
        __syncthreads();
    }
    out[i] = s[threadIdx.x] - v;
    if (threadIdx.x == 255) bs[tile] = s[255];
}

__global__ void scan2b_k(int* __restrict__ bL, int* __restrict__ bC) {
    __shared__ int s[256];
    int* b = blockIdx.x ? bC : bL;
    int nb = blockIdx.x ? 128 : 256;
    int v = (threadIdx.x < nb) ? b[threadIdx.x] : 0;
    s[threadIdx.x] = v;
    __syncthreads();
#pragma unroll
    for (int off = 1; off < 256; off <<= 1) {
        int t = (threadIdx.x >= off) ? s[threadIdx.x - off] : 0;
        __syncthreads();
        s[threadIdx.x] += t;
        __syncthreads();
    }
    if (threadIdx.x < nb) b[threadIdx.x] = s[threadIdx.x] - v;
}

// add block sums, init place cursors, compute invsq = deg ? 1/sqrt(deg) : 0
__global__ void scan3b_k(int* __restrict__ lptr, int* __restrict__ cptr,
                         const int* __restrict__ bsumL, const int* __restrict__ bsumC,
                         int* __restrict__ lcur, int* __restrict__ ccur,
                         const int* __restrict__ ldeg, const int* __restrict__ cdeg,
                         float* __restrict__ invsq_l, float* __restrict__ invsq_c) {
    int b = blockIdx.x, t = threadIdx.x;
    if (b < 256) {
        int i = b * 256 + t;
        int v = lptr[i] + bsumL[b];
        lptr[i] = v; lcur[i] = v;
        int d = ldeg[i];
        invsq_l[i] = d ? rsqrtf((float)d) : 0.0f;
    } else {
        int i = (b - 256) * 256 + t;
        int v = cptr[i] + bsumC[b - 256];
        cptr[i] = v; ccur[i] = v;
        int d = cdeg[i];
        invsq_c[i] = d ? rsqrtf((float)d) : 0.0f;
    }
}

// CSR placement (other endpoint only; norm is separable now)
__global__ void place_k(const int* __restrict__ li, const int* __restrict__ ci,
                        int* __restrict__ lcur, int* __restrict__ ccur,
                        int* __restrict__ l_other, int* __restrict__ c_other) {
    int e = blockIdx.x * 256 + threadIdx.x;
    if (e >= E_) return;
    int l = li[e], c = ci[e];
    int p = atomicAdd(&ccur[c], 1);
    c_other[p] = l;
    int q = atomicAdd(&lcur[l], 1);
    l_other[q] = c;
}

// Fused pull-aggregation, both directions: nodes [0,nC) = clause side, rest = literal.
// Wave per node; msgs are pre-scaled by producer invsq; dest invsq applied here.
__global__ __launch_bounds__(256) void gather2_k(
    const int* __restrict__ cptr, const int* __restrict__ cdeg, const int* __restrict__ c_other,
    const float* __restrict__ lmsg, const float* __restrict__ invsq_c, float* __restrict__ caggr,
    const int* __restrict__ lptr, const int* __restrict__ ldeg, const int* __restrict__ l_other,
    const float* __restrict__ cmsg, const float* __restrict__ invsq_l, float* __restrict__ laggr,
    int nC) {
    int node = (blockIdx.x * 256 + threadIdx.x) >> 6;
    int lane = threadIdx.x & 63;
    bool cside = node < nC;
    int j = cside ? node : node - nC;
    const int* ptr = cside ? cptr : lptr;
    const int* dg  = cside ? cdeg : ldeg;
    const int* oth = cside ? c_other : l_other;
    const float* msg = cside ? lmsg : cmsg;
    float sc = (cside ? invsq_c : invsq_l)[j];
    float* out = cside ? caggr : laggr;
    int s = ptr[j], cnt = dg[j];
    float2 a0 = {0.f, 0.f}, a1 = {0.f, 0.f};
    int k = 0;
    for (; k + 2 <= cnt; k += 2) {
        int o0 = oth[s + k], o1 = oth[s + k + 1];
        const float2 m0 = *(const float2*)&msg[(size_t)o0 * D_ + 2 * lane];
        const float2 m1 = *(const float2*)&msg[(size_t)o1 * D_ + 2 * lane];
        a0.x += m0.x; a0.y += m0.y;
        a1.x += m1.x; a1.y += m1.y;
    }
    if (k < cnt) {
        int o = oth[s + k];
        const float2 m = *(const float2*)&msg[(size_t)o * D_ + 2 * lane];
        a0.x += m.x; a0.y += m.y;
    }
    a0.x = (a0.x + a1.x) * sc;
    a0.y = (a0.y + a1.y) * sc;
    *(float2*)&out[(size_t)j * D_ + 2 * lane] = a0;
}

// ---------- fused 2-layer MLPs, all three in one launch ----------
// blocks [0,nL): l2c on l_cur -> l_msg (scaled by invsq_l)
// blocks [nL,nL+nC): c2l on c_cur -> c_msg (scaled by invsq_c)
// blocks [nL+nC,...): l2l on l_cur with pair-SWAP -> l2lb (unscaled)
__global__ __launch_bounds__(256, 2) void mlp3_k(
    const float* __restrict__ l_cur, const float* __restrict__ c_cur,
    const unsigned short* __restrict__ wt_hi, const unsigned short* __restrict__ wt_lo,
    const float* __restrict__ bb,
    const float* __restrict__ invsq_l, const float* __restrict__ invsq_c,
    float* __restrict__ l_msg, float* __restrict__ c_msg, float* __restrict__ l2lb,
    int nL, int nC) {
    __shared__ char smem[66048];
    unsigned short (*a_hi)[40] = (unsigned short(*)[40])(smem);
    unsigned short (*a_lo)[40] = (unsigned short(*)[40])(smem + 10240);
    unsigned short (*b_hi)[40] = (unsigned short(*)[40])(smem + 20480);
    unsigned short (*b_lo)[40] = (unsigned short(*)[40])(smem + 30720);
    unsigned short* h_hi = (unsigned short*)(smem);          // phase 2 aliases tiles
    unsigned short* h_lo = (unsigned short*)(smem + 32768);
    float* scv = (float*)(smem + 65536);                     // 128 floats, non-aliased

    int b = blockIdx.x, seg, tile;
    if (b < nL)           { seg = 0; tile = b; }
    else if (b < nL + nC) { seg = 1; tile = b - nL; }
    else                  { seg = 2; tile = b - nL - nC; }
    const float* A = (seg == 1) ? c_cur : l_cur;
    float* outp = (seg == 0) ? l_msg : (seg == 1) ? c_msg : l2lb;
    const float* invsq = (seg == 0) ? invsq_l : (seg == 1) ? invsq_c : nullptr;
    const unsigned short* W1h = wt_hi + seg * 32768;
    const unsigned short* W1l = wt_lo + seg * 32768;
    const unsigned short* W2h = W1h + 16384;
    const unsigned short* W2l = W1l + 16384;
    const float* b1v = bb + seg * 256;
    const float* b2v = b1v + 128;
    const int swap = (seg == 2);

    const int t = threadIdx.x;
    const int br0 = tile * 128;
    const int w = t >> 6, lane = t & 63;
    const int wr = w >> 1, wc = w & 1;
    const int quad = lane >> 4, cl = lane & 15;

    if (t < 128) scv[t] = invsq ? invsq[br0 + t] : 1.0f;

    f32x4 acc[4][4];
#pragma unroll
    for (int i = 0; i < 4; i++)
#pragma unroll
        for (int j = 0; j < 4; j++) acc[i][j] = (f32x4){0.f, 0.f, 0.f, 0.f};

    // ---- phase 1: h = A @ W1 ----
    for (int kt = 0; kt < 128; kt += 32) {
#pragma unroll
        for (int i = 0; i < 4; i++) {
            int f = t + 256 * i;
            int r = f >> 3, kq = f & 7;
            int gr = br0 + r;
            if (swap) gr ^= 1;
            const float4 v = *(const float4*)&A[(size_t)gr * D_ + kt + 4 * kq];
            unsigned short h0, l0, h1, l1, h2, l2, h3, l3;
            split2(v.x, h0, l0); split2(v.y, h1, l1);
            split2(v.z, h2, l2); split2(v.w, h3, l3);
            *(ushort4*)&a_hi[r][4 * kq] = make_ushort4(h0, h1, h2, h3);
            *(ushort4*)&a_lo[r][4 * kq] = make_ushort4(l0, l1, l2, l3);
            *(ushort4*)&b_hi[r][4 * kq] = *(const ushort4*)&W1h[(size_t)r * 128 + kt + 4 * kq];
            *(ushort4*)&b_lo[r][4 * kq] = *(const ushort4*)&W1l[(size_t)r * 128 + kt + 4 * kq];
        }
        __syncthreads();
        short8 af_h[4], af_l[4];
#pragma unroll
        for (int i = 0; i < 4; i++) {
            int row = 64 * wr + 16 * i + cl;
            af_h[i] = *(const short8*)&a_hi[row][quad * 8];
            af_l[i] = *(const short8*)&a_lo[row][quad * 8];
        }
#pragma unroll
        for (int j = 0; j < 4; j++) {
            int col = 64 * wc + 16 * j + cl;
            short8 bf_h = *(const short8*)&b_hi[col][quad * 8];
            short8 bf_l = *(const short8*)&b_lo[col][quad * 8];
#pragma unroll
            for (int i = 0; i < 4; i++) {
                acc[i][j] = __builtin_amdgcn_mfma_f32_16x16x32_bf16(af_h[i], bf_h, acc[i][j], 0, 0, 0);
                acc[i][j] = __builtin_amdgcn_mfma_f32_16x16x32_bf16(af_h[i], bf_l, acc[i][j], 0, 0, 0);
                acc[i][j] = __builtin_amdgcn_mfma_f32_16x16x32_bf16(af_l[i], bf_h, acc[i][j], 0, 0, 0);
            }
        }
        __syncthreads();
    }
    // h epilogue: bias + relu + split -> swizzled LDS. C/D: col=cl, row=quad*4+reg.
#pragma unroll
    for (int j = 0; j < 4; j++) {
        int col = 64 * wc + 16 * j + cl;
        float bv = b1v[col];
        int g = col >> 3, go = col & 7;
#pragma unroll
        for (int i = 0; i < 4; i++) {
            int rloc = 64 * wr + 16 * i + quad * 4;
#pragma unroll
            for (int rg = 0; rg < 4; rg++) {
                float v = fmaxf(acc[i][j][rg] + bv, 0.0f);
                unsigned short hh, ll;
                split2(v, hh, ll);
                int r = rloc + rg;
                int off = r * 128 + ((g ^ (r & 15)) << 3) + go;
                h_hi[off] = hh;
                h_lo[off] = ll;
            }
        }
    }
    __syncthreads();
    // ---- phase 2: out = (h @ W2 + b2) * scv ----
#pragma unroll
    for (int i = 0; i < 4; i++)
#pragma unroll
        for (int j = 0; j < 4; j++) acc[i][j] = (f32x4){0.f, 0.f, 0.f, 0.f};

    for (int kt = 0; kt < 128; kt += 32) {
        short8 af_h[4], af_l[4];
        int gbase = (kt >> 3) + quad;
#pragma unroll
        for (int i = 0; i < 4; i++) {
            int r = 64 * wr + 16 * i + cl;
            int off = r * 128 + ((gbase ^ cl) << 3);
            af_h[i] = *(const short8*)&h_hi[off];
            af_l[i] = *(const short8*)&h_lo[off];
        }
#pragma unroll
        for (int j = 0; j < 4; j++) {
            int col = 64 * wc + 16 * j + cl;
            const short8 bf_h = *(const short8*)&W2h[(size_t)col * 128 + kt + quad * 8];
            const short8 bf_l = *(const short8*)&W2l[(size_t)col * 128 + kt + quad * 8];
#pragma unroll
            for (int i = 0; i < 4; i++) {
                acc[i][j] = __builtin_amdgcn_mfma_f32_16x16x32_bf16(af_h[i], bf_h, acc[i][j], 0, 0, 0);
                acc[i][j] = __builtin_amdgcn_mfma_f32_16x16x32_bf16(af_h[i], bf_l, acc[i][j], 0, 0, 0);
                acc[i][j] = __builtin_amdgcn_mfma_f32_16x16x32_bf16(af_l[i], bf_h, acc[i][j], 0, 0, 0);
            }
        }
    }
#pragma unroll
    for (int j = 0; j < 4; j++) {
        int col = 64 * wc + 16 * j + cl;
        float bv = b2v[col];
#pragma unroll
        for (int i = 0; i < 4; i++) {
            int rloc = 64 * wr + 16 * i + quad * 4;
#pragma unroll
            for (int rg = 0; rg < 4; rg++)
                outp[(size_t)(br0 + rloc + rg) * D_ + col] = (acc[i][j][rg] + bv) * scv[rloc + rg];
        }
    }
}

// ---------- fused update GEMMs ----------
// FINAL=0: blocks [0,256) c-update K=256 -> c_nxt; [256,768) l-update K=384 -> l_nxt.
// FINAL=1: all blocks l-update K=384 -> d_out (fp32 or bf16 per flags[0]).
template <int FINAL>
__global__ __launch_bounds__(256, 2) void update_k(
    const float* __restrict__ l_cur, const float* __restrict__ c_cur,
    const float* __restrict__ laggr, const float* __restrict__ caggr,
    const float* __restrict__ l2lb,
    const unsigned short* __restrict__ wt_hi, const unsigned short* __restrict__ wt_lo,
    const float* __restrict__ bb,
    float* __restrict__ c_nxt, float* __restrict__ l_nxt,
    void* __restrict__ dout, const int* __restrict__ flags) {
    __shared__ unsigned short a_hi[128][40], a_lo[128][40];
    __shared__ unsigned short b_hi[128][40], b_lo[128][40];
    const int t = threadIdx.x;
    int b = blockIdx.x;
    const bool cseg = (!FINAL) && (b < 256);
    const int tile = (FINAL || cseg) ? b : b - 256;
    const int K = cseg ? 256 : 384;
    const float* A0 = cseg ? c_cur : l_cur;
    const float* A1 = cseg ? caggr : laggr;
    const float* A2 = l2lb;
    const unsigned short* Wh = wt_hi + (cseg ? 98304 : 131072);
    const unsigned short* Wl = wt_lo + (cseg ? 98304 : 131072);
    const float* bias = bb + (cseg ? 768 : 896);
    const int br0 = tile * 128;
    const int w = t >> 6, lane = t & 63;
    const int wr = w >> 1, wc = w & 1;
    const int quad = lane >> 4, cl = lane & 15;

    f32x4 acc[4][4];
#pragma unroll
    for (int i = 0; i < 4; i++)
#pragma unroll
        for (int j = 0; j < 4; j++) acc[i][j] = (f32x4){0.f, 0.f, 0.f, 0.f};

    for (int kt = 0; kt < K; kt += 32) {
        const float* As = (kt < 128) ? A0 : (kt < 256) ? A1 : A2;
        const int koff = kt & 127;
#pragma unroll
        for (int i = 0; i < 4; i++) {
            int f = t + 256 * i;
            int r = f >> 3, kq = f & 7;
            const float4 v = *(const float4*)&As[(size_t)(br0 + r) * D_ + koff + 4 * kq];
            unsigned short h0, l0, h1, l1, h2, l2, h3, l3;
            split2(v.x, h0, l0); split2(v.y, h1, l1);
            split2(v.z, h2, l2); split2(v.w, h3, l3);
            *(ushort4*)&a_hi[r][4 * kq] = make_ushort4(h0, h1, h2, h3);
            *(ushort4*)&a_lo[r][4 * kq] = make_ushort4(l0, l1, l2, l3);
            *(ushort4*)&b_hi[r][4 * kq] = *(const ushort4*)&Wh[(size_t)r * K + kt + 4 * kq];
            *(ushort4*)&b_lo[r][4 * kq] = *(const ushort4*)&Wl[(size_t)r * K + kt + 4 * kq];
        }
        __syncthreads();
        short8 af_h[4], af_l[4];
#pragma unroll
        for (int i = 0; i < 4; i++) {
            int row = 64 * wr + 16 * i + cl;
            af_h[i] = *(const short8*)&a_hi[row][quad * 8];
            af_l[i] = *(const short8*)&a_lo[row][quad * 8];
        }
#pragma unroll
        for (int j = 0; j < 4; j++) {
            int col = 64 * wc + 16 * j + cl;
            short8 bf_h = *(const short8*)&b_hi[col][quad * 8];
            short8 bf_l = *(const short8*)&b_lo[col][quad * 8];
#pragma unroll
            for (int i = 0; i < 4; i++) {
                acc[i][j] = __builtin_amdgcn_mfma_f32_16x16x32_bf16(af_h[i], bf_h, acc[i][j], 0, 0, 0);
                acc[i][j] = __builtin_amdgcn_mfma_f32_16x16x32_bf16(af_h[i], bf_l, acc[i][j], 0, 0, 0);
                acc[i][j] = __builtin_amdgcn_mfma_f32_16x16x32_bf16(af_l[i], bf_h, acc[i][j], 0, 0, 0);
            }
        }
        __syncthreads();
    }
    const int f32out = FINAL ? flags[0] : 1;
#pragma unroll
    for (int j = 0; j < 4; j++) {
        int col = 64 * wc + 16 * j + cl;
        float bv = bias[col];
#pragma unroll
        for (int i = 0; i < 4; i++) {
            int rbase = br0 + 64 * wr + 16 * i + quad * 4;
#pragma unroll
            for (int rg = 0; rg < 4; rg++) {
                float v = acc[i][j][rg] + bv;
                size_t idx = (size_t)(rbase + rg) * D_ + col;
                if (FINAL) {
                    if (f32out) ((float*)dout)[idx] = v;
                    else        ((bf16*)dout)[idx] = __float2bfloat16(v);
                } else {
                    (cseg ? c_nxt : l_nxt)[idx] = v;
                }
            }
        }
    }
}

extern "C" void kernel_launch(void* const* d_in, const int* in_sizes, int n_in,
                              void* d_out, int out_size, void* d_ws, size_t ws_size,
                              hipStream_t stream) {
    const int* li_raw = (const int*)d_in[0];
    const int* ci_raw = (const int*)d_in[1];

    // ---- workspace layout ----
    float* ws = (float*)d_ws;
    float* lbuf0 = ws;                               // L*D
    float* lbuf1 = lbuf0 + (size_t)L_ * D_;          // L*D
    float* l2lb  = lbuf1 + (size_t)L_ * D_;          // L*D
    float* laggr = l2lb + (size_t)L_ * D_;           // L*D
    float* cbuf0 = laggr + (size_t)L_ * D_;          // C*D
    float* cbuf1 = cbuf0 + (size_t)C_ * D_;          // C*D
    float* caggr = cbuf1 + (size_t)C_ * D_;          // C*D
    float* invsq_l = caggr + (size_t)C_ * D_;        // L
    float* invsq_c = invsq_l + L_;                   // C
    float* bb    = invsq_c + C_;                     // 1024 bias floats
    unsigned short* wt_hi = (unsigned short*)(bb + 1024);   // 180224 ushorts
    unsigned short* wt_lo = wt_hi + 180224;                 // 180224 ushorts
    int*   li    = (int*)(wt_lo + 180224);           // E
    int*   ci    = li + E_;                          // E
    int*   l_other = ci + E_;                        // E
    int*   c_other = l_other + E_;                   // E
    int*   ldegi = c_other + E_;                     // L
    int*   cdegi = ldegi + L_;                       // C
    int*   lptr  = cdegi + C_;                       // L
    int*   cptr  = lptr + L_;                        // C
    int*   lcur  = cptr + C_;                        // L
    int*   ccur  = lcur + L_;                        // C
    int*   bsumL = ccur + C_;                        // 256
    int*   bsumC = bsumL + 256;                      // 128
    int*   flags = bsumC + 128;                      // 2

    // --- dtype detection (device-side, graph-safe) ---
    hipMemsetAsync(flags, 0, 2 * sizeof(int), stream);
    detect_k<<<16, 512, 0, stream>>>((const unsigned short*)d_in[4], li_raw, flags);

    // --- idx fix + degrees (one launch) ---
    hipMemsetAsync(ldegi, 0, (size_t)(L_ + C_) * sizeof(int), stream);
    fixdeg_k<<<2 * E_ / 256, 256, 0, stream>>>(li_raw, ci_raw, li, ci, ldegi, cdegi, flags);

    // --- weight split + bias conversion (one launch) ---
    cvtwb_k<<<708, 256, 0, stream>>>(d_in[4], d_in[6], d_in[8], d_in[10], d_in[12],
                                     d_in[14], d_in[16], d_in[18],
                                     d_in[5], d_in[7], d_in[9], d_in[11], d_in[13],
                                     d_in[15], d_in[17], d_in[19], wt_hi, wt_lo, bb, flags);

    // --- CSR build ---
    scan1b_k<<<384, 256, 0, stream>>>(ldegi, cdegi, lptr, cptr, bsumL, bsumC);
    scan2b_k<<<2, 256, 0, stream>>>(bsumL, bsumC);
    scan3b_k<<<384, 256, 0, stream>>>(lptr, cptr, bsumL, bsumC, lcur, ccur,
                                      ldegi, cdegi, invsq_l, invsq_c);
    place_k<<<E_ / 256, 256, 0, stream>>>(li, ci, lcur, ccur, l_other, c_other);

    // --- broadcast-init embeddings ---
    init2_k<<<(L_ + C_) * D_ / 256, 256, 0, stream>>>(d_in[2], d_in[3], lbuf0, cbuf0, flags);

    float* l_cur = lbuf0; float* l_nxt = lbuf1;
    float* c_cur = cbuf0; float* c_nxt = cbuf1;

    for (int it = 0; it < 3; it++) {
        mlp3_k<<<(L_ / 128) * 2 + C_ / 128, 256, 0, stream>>>(
            l_cur, c_cur, wt_hi, wt_lo, bb, invsq_l, invsq_c,
            l_nxt, c_nxt, l2lb, L_ / 128, C_ / 128);
        gather2_k<<<(C_ + L_) / 4, 256, 0, stream>>>(
            cptr, cdegi, c_other, l_nxt, invsq_c, caggr,
            lptr, ldegi, l_other, c_nxt, invsq_l, laggr, C_);
        update_k<0><<<768, 256, 0, stream>>>(
            l_cur, c_cur, laggr, caggr, l2lb, wt_hi, wt_lo, bb,
            c_nxt, l_nxt, nullptr, flags);
        float* tmp = l_cur; l_cur = l_nxt; l_nxt = tmp;
        tmp = c_cur; c_cur = c_nxt; c_nxt = tmp;
    }
    // --- final iteration: c-update dead -> skip l2c MLP, c-gather, c-update;
    //     fuse output dtype conversion into the l-update epilogue ---
    mlp3_k<<<C_ / 128 + L_ / 128, 256, 0, stream>>>(
        l_cur, c_cur, wt_hi, wt_lo, bb, invsq_l, invsq_c,
        l_nxt, c_nxt, l2lb, 0, C_ / 128);
    gather2_k<<<L_ / 4, 256, 0, stream>>>(
        cptr, cdegi, c_other, l_nxt, invsq_c, caggr,
        lptr, ldegi, l_other, c_nxt, invsq_l, laggr, 0);
    update_k<1><<<512, 256, 0, stream>>>(
        l_cur, c_cur, laggr, caggr, l2lb, wt_hi, wt_lo, bb,
        nullptr, nullptr, d_out, flags);
}